// Round 5
// baseline (699.125 us; speedup 1.0000x reference)
//
#include <hip/hip_runtime.h>

#define NPIX 4096
#define CIN  256
#define DK   32

typedef __attribute__((ext_vector_type(8))) short short8;     // 8 bf16 = one MFMA A/B frag reg group
typedef __attribute__((ext_vector_type(16))) float f32x16;    // 32x32 C/D frag

__device__ __forceinline__ unsigned short f2bf(float f) {
    unsigned int u = __float_as_uint(f);
    return (unsigned short)((u + 0x7fffu + ((u >> 16) & 1u)) >> 16);   // RNE
}
__device__ __forceinline__ float bf2f(unsigned short h) {
    return __uint_as_float(((unsigned int)h) << 16);
}

// ---------------------------------------------------------------------------
// Weight prep (unchanged from r4): wq/wk hi+residual B-frags, wv hi B-frags.
// grid (16 kchunks, 12), 64 threads.
__global__ void wprep_kernel(const float* __restrict__ wq, const float* __restrict__ wk,
                             const float* __restrict__ wv,
                             unsigned short* __restrict__ wqh, unsigned short* __restrict__ wql,
                             unsigned short* __restrict__ wkh, unsigned short* __restrict__ wkl,
                             unsigned short* __restrict__ wvh) {
    const int lane = threadIdx.x & 63, li = lane & 31, hi = lane >> 5;
    const int kc = blockIdx.x, y = blockIdx.y;
    if (y < 4) {
        const float* m = (y < 2) ? wq : wk;
        short8 h8, l8;
#pragma unroll
        for (int e = 0; e < 8; ++e) {
            float v = m[li * CIN + kc * 16 + hi * 8 + e];
            unsigned short hb = f2bf(v);
            h8[e] = (short)hb;
            l8[e] = (short)f2bf(v - bf2f(hb));
        }
        unsigned short* dst = (y == 0) ? wqh : (y == 1) ? wql : (y == 2) ? wkh : wkl;
        *reinterpret_cast<short8*>(&dst[kc * 512 + lane * 8]) = (y & 1) ? l8 : h8;
    } else {
        const int cblk = y - 4;
        short8 h8;
#pragma unroll
        for (int e = 0; e < 8; ++e)
            h8[e] = (short)f2bf(wv[(cblk * 32 + li) * CIN + kc * 16 + hi * 8 + e]);
        *reinterpret_cast<short8*>(&wvh[(cblk * 16 + kc) * 512 + lane * 8]) = h8;
    }
}

// ---------------------------------------------------------------------------
// Fused prep + Q/K/V projection. One block = one 32n tile, x staged in LDS,
// xh/xl frags LDS-only (no global round trip). grid (128, 4), block 512.
// V output uses the sigma-permuted direct D-store (no transpose): elem e of
// lane l holds V[c=l&31][j = 16g + (e&3)+8*(e>>2)+4*(l>>5)] — PV's P B-frags
// use the identical slot->j map, so the MFMA contraction is exact.
__global__ __launch_bounds__(512) void projall_kernel(
        const float* __restrict__ x,
        const unsigned short* __restrict__ wqh, const unsigned short* __restrict__ wql,
        const unsigned short* __restrict__ wkh, const unsigned short* __restrict__ wkl,
        const unsigned short* __restrict__ wvh,
        const float* __restrict__ bq, const float* __restrict__ bk, const float* __restrict__ bv,
        unsigned short* __restrict__ qfrag, unsigned short* __restrict__ kfrag,
        unsigned short* __restrict__ vfrag) {
    __shared__ float xs[64][36];                 // 64c x 32n staging (pad 36)
    __shared__ unsigned short xhf[16 * 512];     // 16 kc frags, 16 KB
    __shared__ unsigned short xlf[16 * 512];
    __shared__ unsigned short ts[2][32][40];     // q/k transpose buffers

    const int t = threadIdx.x, lane = t & 63, li = lane & 31, hi = lane >> 5, w = t >> 6;
    const int nblk = blockIdx.x, b = blockIdx.y;
    const int n0 = nblk * 32;

    for (int cb = 0; cb < 4; ++cb) {
        {   // stage 64c x 32n fp32 (512 float4 units, 1/thread)
            int c = t >> 3, n4 = (t & 7) * 4;
            float4 v = *reinterpret_cast<const float4*>(
                &x[(size_t)(b * CIN + cb * 64 + c) * NPIX + n0 + n4]);
            xs[c][n4 + 0] = v.x; xs[c][n4 + 1] = v.y;
            xs[c][n4 + 2] = v.z; xs[c][n4 + 3] = v.w;
        }
        __syncthreads();
        {   // build frags: waves 0-3 -> xh (kc = w&3), waves 4-7 -> xl
            const int kc = w & 3;
            const bool isL = (w >= 4);
            short8 f;
#pragma unroll
            for (int e = 0; e < 8; ++e) {
                float v = xs[kc * 16 + hi * 8 + e][li];
                unsigned short hb = f2bf(v);
                f[e] = isL ? (short)f2bf(v - bf2f(hb)) : (short)hb;
            }
            unsigned short* dst = isL ? xlf : xhf;
            *reinterpret_cast<short8*>(&dst[(cb * 4 + kc) * 512 + lane * 8]) = f;
        }
        __syncthreads();
    }

    if (w < 2) {
        // Q (w==0) / K (w==1): 3-pass error-compensated MFMA
        const unsigned short* wh = (w == 0) ? wqh : wkh;
        const unsigned short* wl = (w == 0) ? wql : wkl;
        const float* bias = (w == 0) ? bq : bk;
        f32x16 acc;
#pragma unroll
        for (int r = 0; r < 16; ++r) acc[r] = 0.f;
        for (int kc = 0; kc < 16; ++kc) {
            short8 ah = *reinterpret_cast<const short8*>(&xhf[kc * 512 + lane * 8]);
            short8 al = *reinterpret_cast<const short8*>(&xlf[kc * 512 + lane * 8]);
            short8 whf = *reinterpret_cast<const short8*>(&wh[kc * 512 + lane * 8]);
            short8 wlf = *reinterpret_cast<const short8*>(&wl[kc * 512 + lane * 8]);
            acc = __builtin_amdgcn_mfma_f32_32x32x16_bf16(ah, whf, acc, 0, 0, 0);
            acc = __builtin_amdgcn_mfma_f32_32x32x16_bf16(al, whf, acc, 0, 0, 0);
            acc = __builtin_amdgcn_mfma_f32_32x32x16_bf16(ah, wlf, acc, 0, 0, 0);
        }
        const float bs = bias[li];
#pragma unroll
        for (int r = 0; r < 16; ++r) {
            int row = (r & 3) + 8 * (r >> 2) + 4 * hi;      // n-local
            ts[w][row][li] = f2bf(acc[r] + bs);             // [n][d]
        }
        unsigned short* dstf = (w == 0) ? qfrag : kfrag;
#pragma unroll
        for (int dh = 0; dh < 2; ++dh) {
            short8 f = *reinterpret_cast<const short8*>(&ts[w][li][dh * 16 + hi * 8]);
            *reinterpret_cast<short8*>(
                &dstf[((size_t)(b * 128 + nblk) * 2 + dh) * 512 + lane * 8]) = f;
        }
    } else {
        // V: waves 2..7 cover 8 c-blocks (w2<2 take two)
        const int w2 = w - 2;
        const int njob = (w2 < 2) ? 2 : 1;
        for (int jj = 0; jj < njob; ++jj) {
            const int cblk = w2 + jj * 6;
            f32x16 acc;
#pragma unroll
            for (int r = 0; r < 16; ++r) acc[r] = 0.f;
            for (int kc = 0; kc < 16; ++kc) {
                short8 xb = *reinterpret_cast<const short8*>(&xhf[kc * 512 + lane * 8]);
                short8 wf = *reinterpret_cast<const short8*>(&wvh[(cblk * 16 + kc) * 512 + lane * 8]);
                acc = __builtin_amdgcn_mfma_f32_32x32x16_bf16(xb, wf, acc, 0, 0, 0);  // A=xh(m=n), B=wv(n=c)
            }
            const float bvv = bv[cblk * 32 + li];           // c = col = lane&31
#pragma unroll
            for (int g = 0; g < 2; ++g) {
                short8 sv;
#pragma unroll
                for (int e = 0; e < 8; ++e) sv[e] = (short)f2bf(acc[g * 8 + e] + bvv);
                *reinterpret_cast<short8*>(
                    &vfrag[((size_t)(b * 8 + cblk) * 256 + nblk * 2 + g) * 512 + lane * 8]) = sv;
            }
        }
    }
}

// ---------------------------------------------------------------------------
// Fused attention, j-split: each block handles half the j range (2048 j) for a
// 64-i tile; pair partials merged by the last-arriving block (device-scope
// atomic + threadfence). 16 waves: 8 E (2 itile x 4 slices), 8 PV (8 c x 2 it).
// Ps stored in frag-native slot order (sigma-permuted, matches vfrag).
__global__ __launch_bounds__(1024, 8) void attnv_kernel(
        const unsigned short* __restrict__ qfrag, const unsigned short* __restrict__ kfrag,
        const unsigned short* __restrict__ vfrag, const float* __restrict__ xin,
        const float* __restrict__ gamma, unsigned short* __restrict__ opart,
        float* __restrict__ lpart, int* __restrict__ flags, float* __restrict__ out) {
    __shared__ unsigned short Ps[4 * 8 * 512];   // [it*2+buf][jg 8][lane*8], 32 KB
    __shared__ float sred[2][4][32];
    __shared__ int smflag;

    const int t = threadIdx.x, lane = t & 63, li = lane & 31, hi = lane >> 5, w = t >> 6;
    const int blk = blockIdx.x;
    const int xcd = blk & 7, slot = blk >> 3;
    const int jh = slot & 1, ps = slot >> 1;       // pair-mates (blk, blk^8) -> same XCD (heuristic)
    const int p = xcd * 32 + ps;                   // pair id 0..255
    const int b = xcd >> 1;
    const int ipos = (xcd & 1) * 32 + ps;          // 64-i tile in [0,64)
    const bool isE = (w < 8);
    const int itE = (w >> 2) & 1, sl = w & 3;      // E: i-tile, 32j slice
    const int cq = w & 7;                          // PV: 32c chunk

    short8 qb0, qb1;
    float ssum = 0.f;
    short8 kreg[2][2];
    if (isE) {
        size_t qoff = ((size_t)(b * 128 + ipos * 2 + itE) * 2) * 512 + lane * 8;
        qb0 = *reinterpret_cast<const short8*>(&qfrag[qoff]);
        qb1 = *reinterpret_cast<const short8*>(&qfrag[qoff + 512]);
    }

    f32x16 acc0, acc1;
#pragma unroll
    for (int r = 0; r < 16; ++r) { acc0[r] = 0.f; acc1[r] = 0.f; }

    auto load_k = [&](int s, short8* dst) {
        size_t koff = ((size_t)(b * 128 + jh * 64 + s * 4 + sl) * 2) * 512 + lane * 8;
        dst[0] = *reinterpret_cast<const short8*>(&kfrag[koff]);
        dst[1] = *reinterpret_cast<const short8*>(&kfrag[koff + 512]);
    };
    auto do_E = [&](int s, short8* kfr) {
        f32x16 e;
#pragma unroll
        for (int r = 0; r < 16; ++r) e[r] = 0.f;
        e = __builtin_amdgcn_mfma_f32_32x32x16_bf16(kfr[0], qb0, e, 0, 0, 0);  // A=K(m=j), B=Q(n=i)
        e = __builtin_amdgcn_mfma_f32_32x32x16_bf16(kfr[1], qb1, e, 0, 0, 0);
        const int buf = s & 1;
#pragma unroll
        for (int g = 0; g < 2; ++g) {
            short8 pv8;
#pragma unroll
            for (int e2 = 0; e2 < 8; ++e2) {
                float pe = __expf(e[g * 8 + e2]);
                ssum += pe;
                pv8[e2] = (short)f2bf(pe);
            }
            *reinterpret_cast<short8*>(
                &Ps[((itE * 2 + buf) * 8 + sl * 2 + g) * 512 + lane * 8]) = pv8;
        }
    };

    if (isE) { load_k(0, kreg[0]); do_E(0, kreg[0]); load_k(1, kreg[1]); }
    __syncthreads();

    for (int s = 0; s < 16; ++s) {
        if (isE) {
            if (s + 1 < 16) {
                do_E(s + 1, kreg[(s + 1) & 1]);
                if (s + 2 < 16) load_k(s + 2, kreg[s & 1]);
            }
        } else {
            const int buf = s & 1;
            size_t vbase = ((size_t)(b * 8 + cq) * 256 + jh * 128 + s * 8) * 512 + lane * 8;
            short8 vcur = *reinterpret_cast<const short8*>(&vfrag[vbase]);
#pragma unroll
            for (int kc = 0; kc < 8; ++kc) {
                short8 vnext;
                if (kc < 7) vnext = *reinterpret_cast<const short8*>(&vfrag[vbase + (kc + 1) * 512]);
                short8 B0 = *reinterpret_cast<const short8*>(&Ps[(buf * 8 + kc) * 512 + lane * 8]);
                short8 B1 = *reinterpret_cast<const short8*>(&Ps[((2 + buf) * 8 + kc) * 512 + lane * 8]);
                acc0 = __builtin_amdgcn_mfma_f32_32x32x16_bf16(vcur, B0, acc0, 0, 0, 0);
                acc1 = __builtin_amdgcn_mfma_f32_32x32x16_bf16(vcur, B1, acc1, 0, 0, 0);
                vcur = vnext;
            }
        }
        __syncthreads();
    }

    // partial row sums
    if (isE) {
        ssum += __shfl_xor(ssum, 32);
        if (lane < 32) sred[itE][sl][li] = ssum;
    }
    __syncthreads();
    if (isE && sl == 0 && lane < 32) {
        float lt = sred[itE][0][li] + sred[itE][1][li] + sred[itE][2][li] + sred[itE][3][li];
        lpart[((size_t)(p * 2 + jh) * 2 + itE) * 32 + li] = lt;
        sred[itE][0][li] = lt;                       // stash for own merge
    }
    // partial O: jh0 -> fp32 into out; jh1 -> bf16 into opart
    if (!isE) {
#pragma unroll
        for (int it = 0; it < 2; ++it) {
            const f32x16& A = it ? acc1 : acc0;
            if (jh == 0) {
#pragma unroll
                for (int r = 0; r < 16; ++r) {
                    int c = cq * 32 + (r & 3) + 8 * (r >> 2) + 4 * hi;
                    out[(size_t)(b * CIN + c) * NPIX + ipos * 64 + it * 32 + li] = A[r];
                }
            } else {
                size_t ob = (((size_t)p * 8 + cq) * 2 + it) * 1024 + lane * 16;
                short8 s0, s1;
#pragma unroll
                for (int e = 0; e < 8; ++e) { s0[e] = (short)f2bf(A[e]); s1[e] = (short)f2bf(A[8 + e]); }
                *reinterpret_cast<short8*>(&opart[ob])     = s0;
                *reinterpret_cast<short8*>(&opart[ob + 8]) = s1;
            }
        }
    }
    __syncthreads();                                  // drains all stores (vmcnt 0 before barrier)
    if (t == 0) {
        __threadfence();                              // agent-scope release (L2 writeback)
        smflag = atomicAdd(&flags[p], 1);
    }
    __syncthreads();
    if (smflag == 0) return;                          // first arrival: partner will merge
    if (isE) return;
    __threadfence();                                  // acquire side (L1/L2 invalidate)

    // merge (PV waves of the last-arriving block)
    const float l0 = sred[0][0][li] + lpart[((size_t)(p * 2 + (jh ^ 1)) * 2 + 0) * 32 + li];
    const float l1 = sred[1][0][li] + lpart[((size_t)(p * 2 + (jh ^ 1)) * 2 + 1) * 32 + li];
    const float rl[2] = {1.0f / l0, 1.0f / l1};
    const float g = gamma[0];
#pragma unroll
    for (int it = 0; it < 2; ++it) {
        const f32x16& A = it ? acc1 : acc0;
        short8 o0, o1;
        if (jh == 0) {
            size_t ob = (((size_t)p * 8 + cq) * 2 + it) * 1024 + lane * 16;
            o0 = *reinterpret_cast<const short8*>(&opart[ob]);
            o1 = *reinterpret_cast<const short8*>(&opart[ob + 8]);
        }
#pragma unroll
        for (int r = 0; r < 16; ++r) {
            int c = cq * 32 + (r & 3) + 8 * (r >> 2) + 4 * hi;
            size_t idx = (size_t)(b * CIN + c) * NPIX + ipos * 64 + it * 32 + li;
            float oth;
            if (jh == 0) oth = bf2f((unsigned short)(r < 8 ? o0[r] : o1[r - 8]));
            else         oth = out[idx];              // partner's fp32 partial parked in out
            out[idx] = g * (A[r] + oth) * rl[it] + xin[idx];
        }
    }
}

extern "C" void kernel_launch(void* const* d_in, const int* in_sizes, int n_in,
                              void* d_out, int out_size, void* d_ws, size_t ws_size,
                              hipStream_t stream) {
    const float* x     = (const float*)d_in[0];
    const float* wq    = (const float*)d_in[1];
    const float* bq    = (const float*)d_in[2];
    const float* wk    = (const float*)d_in[3];
    const float* bk    = (const float*)d_in[4];
    const float* wv    = (const float*)d_in[5];
    const float* bv    = (const float*)d_in[6];
    const float* gamma = (const float*)d_in[7];
    float* out = (float*)d_out;

    unsigned short* qf    = (unsigned short*)d_ws;       // 1 MB
    unsigned short* kf    = qf + (size_t)524288;         // 1 MB
    unsigned short* vf    = kf + (size_t)524288;         // 8 MB
    unsigned short* wqh   = vf + (size_t)4194304;        // 16 KB
    unsigned short* wql   = wqh + 8192;
    unsigned short* wkh   = wql + 8192;
    unsigned short* wkl   = wkh + 8192;
    unsigned short* wvh   = wkl + 8192;                  // 128 KB
    unsigned short* opart = wvh + 65536;                 // 8 MB (jh1 bf16 partials)
    float*          lpart = (float*)(opart + 4194304);   // 128 KB
    int*            flags = (int*)(lpart + 32768);       // 1 KB
    // total ~19.6 MB of d_ws

    hipMemsetAsync(flags, 0, 256 * sizeof(int), stream);
    wprep_kernel<<<dim3(16, 12), 64, 0, stream>>>(wq, wk, wv, wqh, wql, wkh, wkl, wvh);
    projall_kernel<<<dim3(128, 4), 512, 0, stream>>>(x, wqh, wql, wkh, wkl, wvh,
                                                     bq, bk, bv, qf, kf, vf);
    attnv_kernel<<<dim3(512), 1024, 0, stream>>>(qf, kf, vf, x, gamma,
                                                 opart, lpart, flags, out);
}

// Round 6
// 343.508 us; speedup vs baseline: 2.0353x; 2.0353x over previous
//
#include <hip/hip_runtime.h>

#define NPIX 4096
#define CIN  256
#define DK   32

typedef __attribute__((ext_vector_type(8))) short short8;     // 8 bf16 = one MFMA A/B frag reg group
typedef __attribute__((ext_vector_type(16))) float f32x16;    // 32x32 C/D frag

__device__ __forceinline__ unsigned short f2bf(float f) {
    unsigned int u = __float_as_uint(f);
    return (unsigned short)((u + 0x7fffu + ((u >> 16) & 1u)) >> 16);   // RNE
}
__device__ __forceinline__ float bf2f(unsigned short h) {
    return __uint_as_float(((unsigned int)h) << 16);
}

// ---------------------------------------------------------------------------
// Weight prep: wq/wk hi+residual B-frags, wv hi B-frags.
// grid (16 kchunks, 12), 64 threads.
__global__ void wprep_kernel(const float* __restrict__ wq, const float* __restrict__ wk,
                             const float* __restrict__ wv,
                             unsigned short* __restrict__ wqh, unsigned short* __restrict__ wql,
                             unsigned short* __restrict__ wkh, unsigned short* __restrict__ wkl,
                             unsigned short* __restrict__ wvh) {
    const int lane = threadIdx.x & 63, li = lane & 31, hi = lane >> 5;
    const int kc = blockIdx.x, y = blockIdx.y;
    if (y < 4) {
        const float* m = (y < 2) ? wq : wk;
        short8 h8, l8;
#pragma unroll
        for (int e = 0; e < 8; ++e) {
            float v = m[li * CIN + kc * 16 + hi * 8 + e];
            unsigned short hb = f2bf(v);
            h8[e] = (short)hb;
            l8[e] = (short)f2bf(v - bf2f(hb));
        }
        unsigned short* dst = (y == 0) ? wqh : (y == 1) ? wql : (y == 2) ? wkh : wkl;
        *reinterpret_cast<short8*>(&dst[kc * 512 + lane * 8]) = (y & 1) ? l8 : h8;
    } else {
        const int cblk = y - 4;
        short8 h8;
#pragma unroll
        for (int e = 0; e < 8; ++e)
            h8[e] = (short)f2bf(wv[(cblk * 32 + li) * CIN + kc * 16 + hi * 8 + e]);
        *reinterpret_cast<short8*>(&wvh[(cblk * 16 + kc) * 512 + lane * 8]) = h8;
    }
}

// ---------------------------------------------------------------------------
// Fused prep + Q/K/V projection (unchanged from r5 — measured ~20 us total).
// grid (128, 4), block 512.
__global__ __launch_bounds__(512) void projall_kernel(
        const float* __restrict__ x,
        const unsigned short* __restrict__ wqh, const unsigned short* __restrict__ wql,
        const unsigned short* __restrict__ wkh, const unsigned short* __restrict__ wkl,
        const unsigned short* __restrict__ wvh,
        const float* __restrict__ bq, const float* __restrict__ bk, const float* __restrict__ bv,
        unsigned short* __restrict__ qfrag, unsigned short* __restrict__ kfrag,
        unsigned short* __restrict__ vfrag) {
    __shared__ float xs[64][36];
    __shared__ unsigned short xhf[16 * 512];
    __shared__ unsigned short xlf[16 * 512];
    __shared__ unsigned short ts[2][32][40];

    const int t = threadIdx.x, lane = t & 63, li = lane & 31, hi = lane >> 5, w = t >> 6;
    const int nblk = blockIdx.x, b = blockIdx.y;
    const int n0 = nblk * 32;

    for (int cb = 0; cb < 4; ++cb) {
        {
            int c = t >> 3, n4 = (t & 7) * 4;
            float4 v = *reinterpret_cast<const float4*>(
                &x[(size_t)(b * CIN + cb * 64 + c) * NPIX + n0 + n4]);
            xs[c][n4 + 0] = v.x; xs[c][n4 + 1] = v.y;
            xs[c][n4 + 2] = v.z; xs[c][n4 + 3] = v.w;
        }
        __syncthreads();
        {
            const int kc = w & 3;
            const bool isL = (w >= 4);
            short8 f;
#pragma unroll
            for (int e = 0; e < 8; ++e) {
                float v = xs[kc * 16 + hi * 8 + e][li];
                unsigned short hb = f2bf(v);
                f[e] = isL ? (short)f2bf(v - bf2f(hb)) : (short)hb;
            }
            unsigned short* dst = isL ? xlf : xhf;
            *reinterpret_cast<short8*>(&dst[(cb * 4 + kc) * 512 + lane * 8]) = f;
        }
        __syncthreads();
    }

    if (w < 2) {
        const unsigned short* wh = (w == 0) ? wqh : wkh;
        const unsigned short* wl = (w == 0) ? wql : wkl;
        const float* bias = (w == 0) ? bq : bk;
        f32x16 acc;
#pragma unroll
        for (int r = 0; r < 16; ++r) acc[r] = 0.f;
        for (int kc = 0; kc < 16; ++kc) {
            short8 ah = *reinterpret_cast<const short8*>(&xhf[kc * 512 + lane * 8]);
            short8 al = *reinterpret_cast<const short8*>(&xlf[kc * 512 + lane * 8]);
            short8 whf = *reinterpret_cast<const short8*>(&wh[kc * 512 + lane * 8]);
            short8 wlf = *reinterpret_cast<const short8*>(&wl[kc * 512 + lane * 8]);
            acc = __builtin_amdgcn_mfma_f32_32x32x16_bf16(ah, whf, acc, 0, 0, 0);
            acc = __builtin_amdgcn_mfma_f32_32x32x16_bf16(al, whf, acc, 0, 0, 0);
            acc = __builtin_amdgcn_mfma_f32_32x32x16_bf16(ah, wlf, acc, 0, 0, 0);
        }
        const float bs = bias[li];
#pragma unroll
        for (int r = 0; r < 16; ++r) {
            int row = (r & 3) + 8 * (r >> 2) + 4 * hi;
            ts[w][row][li] = f2bf(acc[r] + bs);
        }
        unsigned short* dstf = (w == 0) ? qfrag : kfrag;
#pragma unroll
        for (int dh = 0; dh < 2; ++dh) {
            short8 f = *reinterpret_cast<const short8*>(&ts[w][li][dh * 16 + hi * 8]);
            *reinterpret_cast<short8*>(
                &dstf[((size_t)(b * 128 + nblk) * 2 + dh) * 512 + lane * 8]) = f;
        }
    } else {
        const int w2 = w - 2;
        const int njob = (w2 < 2) ? 2 : 1;
        for (int jj = 0; jj < njob; ++jj) {
            const int cblk = w2 + jj * 6;
            f32x16 acc;
#pragma unroll
            for (int r = 0; r < 16; ++r) acc[r] = 0.f;
            for (int kc = 0; kc < 16; ++kc) {
                short8 xb = *reinterpret_cast<const short8*>(&xhf[kc * 512 + lane * 8]);
                short8 wf = *reinterpret_cast<const short8*>(&wvh[(cblk * 16 + kc) * 512 + lane * 8]);
                acc = __builtin_amdgcn_mfma_f32_32x32x16_bf16(xb, wf, acc, 0, 0, 0);
            }
            const float bvv = bv[cblk * 32 + li];
#pragma unroll
            for (int g = 0; g < 2; ++g) {
                short8 sv;
#pragma unroll
                for (int e = 0; e < 8; ++e) sv[e] = (short)f2bf(acc[g * 8 + e] + bvv);
                *reinterpret_cast<short8*>(
                    &vfrag[((size_t)(b * 8 + cblk) * 256 + nblk * 2 + g) * 512 + lane * 8]) = sv;
            }
        }
    }
}

// ---------------------------------------------------------------------------
// Fused attention, j-split, 768 threads (12 waves = 4 E + 8 PV), 2 blocks/CU.
// E wave sl handles its 32-j slice for BOTH i-tiles. Pair merge via atomic flag.
__global__ __launch_bounds__(768, 6) void attnv_kernel(
        const unsigned short* __restrict__ qfrag, const unsigned short* __restrict__ kfrag,
        const unsigned short* __restrict__ vfrag, const float* __restrict__ xin,
        const float* __restrict__ gamma, unsigned short* __restrict__ opart,
        float* __restrict__ lpart, int* __restrict__ flags, float* __restrict__ out) {
    __shared__ unsigned short Ps[4 * 8 * 512];   // [it*2+buf][jg 8][lane*8], 32 KB
    __shared__ float sred[2][4][32];
    __shared__ int smflag;

    const int t = threadIdx.x, lane = t & 63, li = lane & 31, hi = lane >> 5, w = t >> 6;
    const int blk = blockIdx.x;
    const int xcd = blk & 7, slot = blk >> 3;
    const int jh = slot & 1, ps = slot >> 1;
    const int p = xcd * 32 + ps;                   // pair id 0..255
    const int b = xcd >> 1;
    const int ipos = (xcd & 1) * 32 + ps;          // 64-i tile in [0,64)
    const bool isE = (w < 4);
    const int sl = w & 3;                          // E: 32-j slice
    const int cq = w - 4;                          // PV: 32c chunk

    short8 qb[2][2];
    float ssum[2] = {0.f, 0.f};
    if (isE) {
#pragma unroll
        for (int it = 0; it < 2; ++it) {
            size_t qoff = ((size_t)(b * 128 + ipos * 2 + it) * 2) * 512 + lane * 8;
            qb[it][0] = *reinterpret_cast<const short8*>(&qfrag[qoff]);
            qb[it][1] = *reinterpret_cast<const short8*>(&qfrag[qoff + 512]);
        }
    }

    f32x16 acc0, acc1;
#pragma unroll
    for (int r = 0; r < 16; ++r) { acc0[r] = 0.f; acc1[r] = 0.f; }

    auto do_E = [&](int s) {
        const int buf = s & 1;
        size_t koff = ((size_t)(b * 128 + jh * 64 + s * 4 + sl) * 2) * 512 + lane * 8;
        short8 k0 = *reinterpret_cast<const short8*>(&kfrag[koff]);
        short8 k1 = *reinterpret_cast<const short8*>(&kfrag[koff + 512]);
#pragma unroll
        for (int it = 0; it < 2; ++it) {
            f32x16 e;
#pragma unroll
            for (int r = 0; r < 16; ++r) e[r] = 0.f;
            e = __builtin_amdgcn_mfma_f32_32x32x16_bf16(k0, qb[it][0], e, 0, 0, 0);
            e = __builtin_amdgcn_mfma_f32_32x32x16_bf16(k1, qb[it][1], e, 0, 0, 0);
#pragma unroll
            for (int g = 0; g < 2; ++g) {
                short8 pv8;
#pragma unroll
                for (int e2 = 0; e2 < 8; ++e2) {
                    float pe = __expf(e[g * 8 + e2]);
                    ssum[it] += pe;
                    pv8[e2] = (short)f2bf(pe);
                }
                *reinterpret_cast<short8*>(
                    &Ps[((it * 2 + buf) * 8 + sl * 2 + g) * 512 + lane * 8]) = pv8;
            }
        }
    };

    if (isE) do_E(0);
    __syncthreads();

    for (int s = 0; s < 16; ++s) {
        if (isE) {
            if (s + 1 < 16) do_E(s + 1);
        } else {
            const int buf = s & 1;
            size_t vbase = ((size_t)(b * 8 + cq) * 256 + jh * 128 + s * 8) * 512 + lane * 8;
            short8 vcur = *reinterpret_cast<const short8*>(&vfrag[vbase]);
#pragma unroll
            for (int kc = 0; kc < 8; ++kc) {
                short8 vnext;
                if (kc < 7) vnext = *reinterpret_cast<const short8*>(&vfrag[vbase + (kc + 1) * 512]);
                short8 B0 = *reinterpret_cast<const short8*>(&Ps[(buf * 8 + kc) * 512 + lane * 8]);
                short8 B1 = *reinterpret_cast<const short8*>(&Ps[((2 + buf) * 8 + kc) * 512 + lane * 8]);
                acc0 = __builtin_amdgcn_mfma_f32_32x32x16_bf16(vcur, B0, acc0, 0, 0, 0);
                acc1 = __builtin_amdgcn_mfma_f32_32x32x16_bf16(vcur, B1, acc1, 0, 0, 0);
                vcur = vnext;
            }
        }
        __syncthreads();
    }

    // partial row sums
    if (isE) {
#pragma unroll
        for (int it = 0; it < 2; ++it) {
            ssum[it] += __shfl_xor(ssum[it], 32);
            if (lane < 32) sred[it][sl][li] = ssum[it];
        }
    }
    __syncthreads();
    if (isE && sl == 0 && lane < 32) {
#pragma unroll
        for (int it = 0; it < 2; ++it) {
            float lt = sred[it][0][li] + sred[it][1][li] + sred[it][2][li] + sred[it][3][li];
            lpart[((size_t)(p * 2 + jh) * 2 + it) * 32 + li] = lt;
            sred[it][0][li] = lt;                  // stash for own merge
        }
    }
    // partial O: jh0 -> fp32 parked in out; jh1 -> bf16 into opart
    if (!isE) {
#pragma unroll
        for (int it = 0; it < 2; ++it) {
            const f32x16& A = it ? acc1 : acc0;
            if (jh == 0) {
#pragma unroll
                for (int r = 0; r < 16; ++r) {
                    int c = cq * 32 + (r & 3) + 8 * (r >> 2) + 4 * hi;
                    out[(size_t)(b * CIN + c) * NPIX + ipos * 64 + it * 32 + li] = A[r];
                }
            } else {
                size_t ob = (((size_t)p * 8 + cq) * 2 + it) * 1024 + lane * 16;
                short8 s0, s1;
#pragma unroll
                for (int e = 0; e < 8; ++e) { s0[e] = (short)f2bf(A[e]); s1[e] = (short)f2bf(A[8 + e]); }
                *reinterpret_cast<short8*>(&opart[ob])     = s0;
                *reinterpret_cast<short8*>(&opart[ob + 8]) = s1;
            }
        }
    }
    __syncthreads();
    if (t == 0) {
        __threadfence();                              // release: partial stores visible device-wide
        smflag = atomicAdd(&flags[p], 1);
    }
    __syncthreads();
    if (smflag == 0) return;                          // first arrival: partner merges
    if (isE) return;
    __threadfence();                                  // acquire

    // merge (PV waves of the last-arriving block)
    const float l0 = sred[0][0][li] + lpart[((size_t)(p * 2 + (jh ^ 1)) * 2 + 0) * 32 + li];
    const float l1 = sred[1][0][li] + lpart[((size_t)(p * 2 + (jh ^ 1)) * 2 + 1) * 32 + li];
    const float rl[2] = {1.0f / l0, 1.0f / l1};
    const float g = gamma[0];
#pragma unroll
    for (int it = 0; it < 2; ++it) {
        const f32x16& A = it ? acc1 : acc0;
        short8 o0, o1;
        if (jh == 0) {
            size_t ob = (((size_t)p * 8 + cq) * 2 + it) * 1024 + lane * 16;
            o0 = *reinterpret_cast<const short8*>(&opart[ob]);
            o1 = *reinterpret_cast<const short8*>(&opart[ob + 8]);
        }
#pragma unroll
        for (int r = 0; r < 16; ++r) {
            int c = cq * 32 + (r & 3) + 8 * (r >> 2) + 4 * hi;
            size_t idx = (size_t)(b * CIN + c) * NPIX + ipos * 64 + it * 32 + li;
            float oth;
            if (jh == 0) oth = bf2f((unsigned short)(r < 8 ? o0[r] : o1[r - 8]));
            else         oth = out[idx];              // partner's fp32 partial parked in out
            out[idx] = g * (A[r] + oth) * rl[it] + xin[idx];
        }
    }
}

extern "C" void kernel_launch(void* const* d_in, const int* in_sizes, int n_in,
                              void* d_out, int out_size, void* d_ws, size_t ws_size,
                              hipStream_t stream) {
    const float* x     = (const float*)d_in[0];
    const float* wq    = (const float*)d_in[1];
    const float* bq    = (const float*)d_in[2];
    const float* wk    = (const float*)d_in[3];
    const float* bk    = (const float*)d_in[4];
    const float* wv    = (const float*)d_in[5];
    const float* bv    = (const float*)d_in[6];
    const float* gamma = (const float*)d_in[7];
    float* out = (float*)d_out;

    unsigned short* qf    = (unsigned short*)d_ws;       // 1 MB
    unsigned short* kf    = qf + (size_t)524288;         // 1 MB
    unsigned short* vf    = kf + (size_t)524288;         // 8 MB
    unsigned short* wqh   = vf + (size_t)4194304;
    unsigned short* wql   = wqh + 8192;
    unsigned short* wkh   = wql + 8192;
    unsigned short* wkl   = wkh + 8192;
    unsigned short* wvh   = wkl + 8192;                  // 128 KB
    unsigned short* opart = wvh + 65536;                 // 8 MB
    float*          lpart = (float*)(opart + 4194304);   // 128 KB
    int*            flags = (int*)(lpart + 32768);       // 1 KB

    hipMemsetAsync(flags, 0, 256 * sizeof(int), stream);
    wprep_kernel<<<dim3(16, 12), 64, 0, stream>>>(wq, wk, wv, wqh, wql, wkh, wkl, wvh);
    projall_kernel<<<dim3(128, 4), 512, 0, stream>>>(x, wqh, wql, wkh, wkl, wvh,
                                                     bq, bk, bv, qf, kf, vf);
    attnv_kernel<<<dim3(512), 768, 0, stream>>>(qf, kf, vf, x, gamma,
                                                opart, lpart, flags, out);
}

// Round 7
// 239.857 us; speedup vs baseline: 2.9148x; 1.4321x over previous
//
#include <hip/hip_runtime.h>

#define NPIX 4096
#define CIN  256
#define DK   32

typedef __attribute__((ext_vector_type(8))) short short8;     // 8 bf16 = one MFMA A/B frag reg group
typedef __attribute__((ext_vector_type(16))) float f32x16;    // 32x32 C/D frag

__device__ __forceinline__ unsigned short f2bf(float f) {
    unsigned int u = __float_as_uint(f);
    return (unsigned short)((u + 0x7fffu + ((u >> 16) & 1u)) >> 16);   // RNE
}
__device__ __forceinline__ float bf2f(unsigned short h) {
    return __uint_as_float(((unsigned int)h) << 16);
}

// ---------------------------------------------------------------------------
// Weight prep: wq/wk hi+residual B-frags, wv hi B-frags.
// grid (16 kchunks, 12), 64 threads.
__global__ void wprep_kernel(const float* __restrict__ wq, const float* __restrict__ wk,
                             const float* __restrict__ wv,
                             unsigned short* __restrict__ wqh, unsigned short* __restrict__ wql,
                             unsigned short* __restrict__ wkh, unsigned short* __restrict__ wkl,
                             unsigned short* __restrict__ wvh) {
    const int lane = threadIdx.x & 63, li = lane & 31, hi = lane >> 5;
    const int kc = blockIdx.x, y = blockIdx.y;
    if (y < 4) {
        const float* m = (y < 2) ? wq : wk;
        short8 h8, l8;
#pragma unroll
        for (int e = 0; e < 8; ++e) {
            float v = m[li * CIN + kc * 16 + hi * 8 + e];
            unsigned short hb = f2bf(v);
            h8[e] = (short)hb;
            l8[e] = (short)f2bf(v - bf2f(hb));
        }
        unsigned short* dst = (y == 0) ? wqh : (y == 1) ? wql : (y == 2) ? wkh : wkl;
        *reinterpret_cast<short8*>(&dst[kc * 512 + lane * 8]) = (y & 1) ? l8 : h8;
    } else {
        const int cblk = y - 4;
        short8 h8;
#pragma unroll
        for (int e = 0; e < 8; ++e)
            h8[e] = (short)f2bf(wv[(cblk * 32 + li) * CIN + kc * 16 + hi * 8 + e]);
        *reinterpret_cast<short8*>(&wvh[(cblk * 16 + kc) * 512 + lane * 8]) = h8;
    }
}

// ---------------------------------------------------------------------------
// Fused prep + Q/K/V projection (unchanged — measured ~20 us total).
// grid (128, 4), block 512.
__global__ __launch_bounds__(512) void projall_kernel(
        const float* __restrict__ x,
        const unsigned short* __restrict__ wqh, const unsigned short* __restrict__ wql,
        const unsigned short* __restrict__ wkh, const unsigned short* __restrict__ wkl,
        const unsigned short* __restrict__ wvh,
        const float* __restrict__ bq, const float* __restrict__ bk, const float* __restrict__ bv,
        unsigned short* __restrict__ qfrag, unsigned short* __restrict__ kfrag,
        unsigned short* __restrict__ vfrag) {
    __shared__ float xs[64][36];
    __shared__ unsigned short xhf[16 * 512];
    __shared__ unsigned short xlf[16 * 512];
    __shared__ unsigned short ts[2][32][40];

    const int t = threadIdx.x, lane = t & 63, li = lane & 31, hi = lane >> 5, w = t >> 6;
    const int nblk = blockIdx.x, b = blockIdx.y;
    const int n0 = nblk * 32;

    for (int cb = 0; cb < 4; ++cb) {
        {
            int c = t >> 3, n4 = (t & 7) * 4;
            float4 v = *reinterpret_cast<const float4*>(
                &x[(size_t)(b * CIN + cb * 64 + c) * NPIX + n0 + n4]);
            xs[c][n4 + 0] = v.x; xs[c][n4 + 1] = v.y;
            xs[c][n4 + 2] = v.z; xs[c][n4 + 3] = v.w;
        }
        __syncthreads();
        {
            const int kc = w & 3;
            const bool isL = (w >= 4);
            short8 f;
#pragma unroll
            for (int e = 0; e < 8; ++e) {
                float v = xs[kc * 16 + hi * 8 + e][li];
                unsigned short hb = f2bf(v);
                f[e] = isL ? (short)f2bf(v - bf2f(hb)) : (short)hb;
            }
            unsigned short* dst = isL ? xlf : xhf;
            *reinterpret_cast<short8*>(&dst[(cb * 4 + kc) * 512 + lane * 8]) = f;
        }
        __syncthreads();
    }

    if (w < 2) {
        const unsigned short* wh = (w == 0) ? wqh : wkh;
        const unsigned short* wl = (w == 0) ? wql : wkl;
        const float* bias = (w == 0) ? bq : bk;
        f32x16 acc;
#pragma unroll
        for (int r = 0; r < 16; ++r) acc[r] = 0.f;
        for (int kc = 0; kc < 16; ++kc) {
            short8 ah = *reinterpret_cast<const short8*>(&xhf[kc * 512 + lane * 8]);
            short8 al = *reinterpret_cast<const short8*>(&xlf[kc * 512 + lane * 8]);
            short8 whf = *reinterpret_cast<const short8*>(&wh[kc * 512 + lane * 8]);
            short8 wlf = *reinterpret_cast<const short8*>(&wl[kc * 512 + lane * 8]);
            acc = __builtin_amdgcn_mfma_f32_32x32x16_bf16(ah, whf, acc, 0, 0, 0);
            acc = __builtin_amdgcn_mfma_f32_32x32x16_bf16(al, whf, acc, 0, 0, 0);
            acc = __builtin_amdgcn_mfma_f32_32x32x16_bf16(ah, wlf, acc, 0, 0, 0);
        }
        const float bs = bias[li];
#pragma unroll
        for (int r = 0; r < 16; ++r) {
            int row = (r & 3) + 8 * (r >> 2) + 4 * hi;
            ts[w][row][li] = f2bf(acc[r] + bs);
        }
        unsigned short* dstf = (w == 0) ? qfrag : kfrag;
#pragma unroll
        for (int dh = 0; dh < 2; ++dh) {
            short8 f = *reinterpret_cast<const short8*>(&ts[w][li][dh * 16 + hi * 8]);
            *reinterpret_cast<short8*>(
                &dstf[((size_t)(b * 128 + nblk) * 2 + dh) * 512 + lane * 8]) = f;
        }
    } else {
        const int w2 = w - 2;
        const int njob = (w2 < 2) ? 2 : 1;
        for (int jj = 0; jj < njob; ++jj) {
            const int cblk = w2 + jj * 6;
            f32x16 acc;
#pragma unroll
            for (int r = 0; r < 16; ++r) acc[r] = 0.f;
            for (int kc = 0; kc < 16; ++kc) {
                short8 xb = *reinterpret_cast<const short8*>(&xhf[kc * 512 + lane * 8]);
                short8 wf = *reinterpret_cast<const short8*>(&wvh[(cblk * 16 + kc) * 512 + lane * 8]);
                acc = __builtin_amdgcn_mfma_f32_32x32x16_bf16(xb, wf, acc, 0, 0, 0);
            }
            const float bvv = bv[cblk * 32 + li];
#pragma unroll
            for (int g = 0; g < 2; ++g) {
                short8 sv;
#pragma unroll
                for (int e = 0; e < 8; ++e) sv[e] = (short)f2bf(acc[g * 8 + e] + bvv);
                *reinterpret_cast<short8*>(
                    &vfrag[((size_t)(b * 8 + cblk) * 256 + nblk * 2 + g) * 512 + lane * 8]) = sv;
            }
        }
    }
}

// ---------------------------------------------------------------------------
// Fused attention, j-split, 768 threads (12 waves = 4 E + 8 PV), 2 blocks/CU.
// NO device fences: blocks write partials and exit; merge_kernel combines.
// jh0 partial O parked fp32 in out; jh1 partial O bf16 in opart.
__global__ __launch_bounds__(768, 6) void attnv_kernel(
        const unsigned short* __restrict__ qfrag, const unsigned short* __restrict__ kfrag,
        const unsigned short* __restrict__ vfrag, unsigned short* __restrict__ opart,
        float* __restrict__ lpart, float* __restrict__ out) {
    __shared__ unsigned short Ps[4 * 8 * 512];   // [it*2+buf][jg 8][lane*8], 32 KB
    __shared__ float sred[2][4][32];

    const int t = threadIdx.x, lane = t & 63, li = lane & 31, hi = lane >> 5, w = t >> 6;
    const int blk = blockIdx.x;
    const int xcd = blk & 7, slot = blk >> 3;
    const int jh = slot & 1, ps = slot >> 1;
    const int b = xcd >> 1;
    const int ipos = (xcd & 1) * 32 + ps;          // 64-i tile in [0,64)
    const bool isE = (w < 4);
    const int sl = w & 3;                          // E: 32-j slice
    const int cq = w - 4;                          // PV: 32c chunk

    short8 qb[2][2];
    float ssum[2] = {0.f, 0.f};
    if (isE) {
#pragma unroll
        for (int it = 0; it < 2; ++it) {
            size_t qoff = ((size_t)(b * 128 + ipos * 2 + it) * 2) * 512 + lane * 8;
            qb[it][0] = *reinterpret_cast<const short8*>(&qfrag[qoff]);
            qb[it][1] = *reinterpret_cast<const short8*>(&qfrag[qoff + 512]);
        }
    }

    f32x16 acc0, acc1;
#pragma unroll
    for (int r = 0; r < 16; ++r) { acc0[r] = 0.f; acc1[r] = 0.f; }

    auto do_E = [&](int s) {
        const int buf = s & 1;
        size_t koff = ((size_t)(b * 128 + jh * 64 + s * 4 + sl) * 2) * 512 + lane * 8;
        short8 k0 = *reinterpret_cast<const short8*>(&kfrag[koff]);
        short8 k1 = *reinterpret_cast<const short8*>(&kfrag[koff + 512]);
#pragma unroll
        for (int it = 0; it < 2; ++it) {
            f32x16 e;
#pragma unroll
            for (int r = 0; r < 16; ++r) e[r] = 0.f;
            e = __builtin_amdgcn_mfma_f32_32x32x16_bf16(k0, qb[it][0], e, 0, 0, 0);
            e = __builtin_amdgcn_mfma_f32_32x32x16_bf16(k1, qb[it][1], e, 0, 0, 0);
#pragma unroll
            for (int g = 0; g < 2; ++g) {
                short8 pv8;
#pragma unroll
                for (int e2 = 0; e2 < 8; ++e2) {
                    float pe = __expf(e[g * 8 + e2]);
                    ssum[it] += pe;
                    pv8[e2] = (short)f2bf(pe);
                }
                *reinterpret_cast<short8*>(
                    &Ps[((it * 2 + buf) * 8 + sl * 2 + g) * 512 + lane * 8]) = pv8;
            }
        }
    };

    if (isE) do_E(0);
    __syncthreads();

    for (int s = 0; s < 16; ++s) {
        if (isE) {
            if (s + 1 < 16) do_E(s + 1);
        } else {
            const int buf = s & 1;
            size_t vbase = ((size_t)(b * 8 + cq) * 256 + jh * 128 + s * 8) * 512 + lane * 8;
            short8 vcur = *reinterpret_cast<const short8*>(&vfrag[vbase]);
#pragma unroll
            for (int kc = 0; kc < 8; ++kc) {
                short8 vnext;
                if (kc < 7) vnext = *reinterpret_cast<const short8*>(&vfrag[vbase + (kc + 1) * 512]);
                short8 B0 = *reinterpret_cast<const short8*>(&Ps[(buf * 8 + kc) * 512 + lane * 8]);
                short8 B1 = *reinterpret_cast<const short8*>(&Ps[((2 + buf) * 8 + kc) * 512 + lane * 8]);
                acc0 = __builtin_amdgcn_mfma_f32_32x32x16_bf16(vcur, B0, acc0, 0, 0, 0);
                acc1 = __builtin_amdgcn_mfma_f32_32x32x16_bf16(vcur, B1, acc1, 0, 0, 0);
                vcur = vnext;
            }
        }
        __syncthreads();
    }

    // partial row sums -> lpart[jh][b][i] (linear i)
    if (isE) {
#pragma unroll
        for (int it = 0; it < 2; ++it) {
            ssum[it] += __shfl_xor(ssum[it], 32);
            if (lane < 32) sred[it][sl][li] = ssum[it];
        }
    }
    __syncthreads();
    if (isE && sl == 0 && lane < 32) {
#pragma unroll
        for (int it = 0; it < 2; ++it) {
            float lt = sred[it][0][li] + sred[it][1][li] + sred[it][2][li] + sred[it][3][li];
            lpart[((size_t)jh * 4 + b) * NPIX + ipos * 64 + it * 32 + li] = lt;
        }
    }
    // partial O (linear [b][c][i]): jh0 fp32 parked in out, jh1 bf16 in opart
    if (!isE) {
#pragma unroll
        for (int it = 0; it < 2; ++it) {
            const f32x16& A = it ? acc1 : acc0;
#pragma unroll
            for (int r = 0; r < 16; ++r) {
                int c = cq * 32 + (r & 3) + 8 * (r >> 2) + 4 * hi;
                size_t idx = (size_t)(b * CIN + c) * NPIX + ipos * 64 + it * 32 + li;
                if (jh == 0) out[idx] = A[r];
                else         opart[idx] = f2bf(A[r]);
            }
        }
    }
}

// ---------------------------------------------------------------------------
// Merge: out = gamma * (O0 + O1) / (l0 + l1) + x.  Pure streaming, ~59 MB.
// grid 4096, block 256; thread handles 4 consecutive i.
__global__ __launch_bounds__(256) void merge_kernel(
        const unsigned short* __restrict__ opart, const float* __restrict__ lpart,
        const float* __restrict__ xin, const float* __restrict__ gamma,
        float* __restrict__ out) {
    const size_t idx4 = ((size_t)blockIdx.x * 256 + threadIdx.x) * 4;
    const size_t i  = idx4 & (NPIX - 1);
    const size_t b  = idx4 >> 20;                 // idx4 / (CIN*NPIX)
    float4 o0 = *reinterpret_cast<const float4*>(&out[idx4]);
    float4 xv = *reinterpret_cast<const float4*>(&xin[idx4]);
    float4 l0 = *reinterpret_cast<const float4*>(&lpart[b * NPIX + i]);
    float4 l1 = *reinterpret_cast<const float4*>(&lpart[(4 + b) * NPIX + i]);
    const unsigned short* op = &opart[idx4];
    const float g = gamma[0];
    float4 o;
    o.x = g * (o0.x + bf2f(op[0])) / (l0.x + l1.x) + xv.x;
    o.y = g * (o0.y + bf2f(op[1])) / (l0.y + l1.y) + xv.y;
    o.z = g * (o0.z + bf2f(op[2])) / (l0.z + l1.z) + xv.z;
    o.w = g * (o0.w + bf2f(op[3])) / (l0.w + l1.w) + xv.w;
    *reinterpret_cast<float4*>(&out[idx4]) = o;
}

extern "C" void kernel_launch(void* const* d_in, const int* in_sizes, int n_in,
                              void* d_out, int out_size, void* d_ws, size_t ws_size,
                              hipStream_t stream) {
    const float* x     = (const float*)d_in[0];
    const float* wq    = (const float*)d_in[1];
    const float* bq    = (const float*)d_in[2];
    const float* wk    = (const float*)d_in[3];
    const float* bk    = (const float*)d_in[4];
    const float* wv    = (const float*)d_in[5];
    const float* bv    = (const float*)d_in[6];
    const float* gamma = (const float*)d_in[7];
    float* out = (float*)d_out;

    unsigned short* qf    = (unsigned short*)d_ws;       // 1 MB
    unsigned short* kf    = qf + (size_t)524288;         // 1 MB
    unsigned short* vf    = kf + (size_t)524288;         // 8 MB
    unsigned short* wqh   = vf + (size_t)4194304;
    unsigned short* wql   = wqh + 8192;
    unsigned short* wkh   = wql + 8192;
    unsigned short* wkl   = wkh + 8192;
    unsigned short* wvh   = wkl + 8192;                  // 160 KB of weight frags
    unsigned short* opart = wvh + 65536;                 // 8.4 MB (jh1 bf16 partial O)
    float*          lpart = (float*)(opart + 4194304);   // 128 KB
    // total ~18.8 MB of d_ws

    wprep_kernel<<<dim3(16, 12), 64, 0, stream>>>(wq, wk, wv, wqh, wql, wkh, wkl, wvh);
    projall_kernel<<<dim3(128, 4), 512, 0, stream>>>(x, wqh, wql, wkh, wkl, wvh,
                                                     bq, bk, bv, qf, kf, vf);
    attnv_kernel<<<dim3(512), 768, 0, stream>>>(qf, kf, vf, opart, lpart, out);
    merge_kernel<<<dim3(4096), 256, 0, stream>>>(opart, lpart, x, gamma, out);
}

// Round 8
// 145.366 us; speedup vs baseline: 4.8094x; 1.6500x over previous
//
#include <hip/hip_runtime.h>

#define NPIX 4096
#define CIN  256
#define DK   32

typedef __attribute__((ext_vector_type(8))) short short8;     // 8 bf16 = one MFMA A/B frag reg group
typedef __attribute__((ext_vector_type(16))) float f32x16;    // 32x32 C/D frag

__device__ __forceinline__ unsigned short f2bf(float f) {
    unsigned int u = __float_as_uint(f);
    return (unsigned short)((u + 0x7fffu + ((u >> 16) & 1u)) >> 16);   // RNE
}
__device__ __forceinline__ float bf2f(unsigned short h) {
    return __uint_as_float(((unsigned int)h) << 16);
}

// ---------------------------------------------------------------------------
// Weight prep: wq/wk hi+residual B-frags, wv hi B-frags.
// grid (16 kchunks, 12), 64 threads.
__global__ void wprep_kernel(const float* __restrict__ wq, const float* __restrict__ wk,
                             const float* __restrict__ wv,
                             unsigned short* __restrict__ wqh, unsigned short* __restrict__ wql,
                             unsigned short* __restrict__ wkh, unsigned short* __restrict__ wkl,
                             unsigned short* __restrict__ wvh) {
    const int lane = threadIdx.x & 63, li = lane & 31, hi = lane >> 5;
    const int kc = blockIdx.x, y = blockIdx.y;
    if (y < 4) {
        const float* m = (y < 2) ? wq : wk;
        short8 h8, l8;
#pragma unroll
        for (int e = 0; e < 8; ++e) {
            float v = m[li * CIN + kc * 16 + hi * 8 + e];
            unsigned short hb = f2bf(v);
            h8[e] = (short)hb;
            l8[e] = (short)f2bf(v - bf2f(hb));
        }
        unsigned short* dst = (y == 0) ? wqh : (y == 1) ? wql : (y == 2) ? wkh : wkl;
        *reinterpret_cast<short8*>(&dst[kc * 512 + lane * 8]) = (y & 1) ? l8 : h8;
    } else {
        const int cblk = y - 4;
        short8 h8;
#pragma unroll
        for (int e = 0; e < 8; ++e)
            h8[e] = (short)f2bf(wv[(cblk * 32 + li) * CIN + kc * 16 + hi * 8 + e]);
        *reinterpret_cast<short8*>(&wvh[(cblk * 16 + kc) * 512 + lane * 8]) = h8;
    }
}

// ---------------------------------------------------------------------------
// Fused prep + Q/K/V projection (unchanged). grid (128, 4), block 512.
__global__ __launch_bounds__(512) void projall_kernel(
        const float* __restrict__ x,
        const unsigned short* __restrict__ wqh, const unsigned short* __restrict__ wql,
        const unsigned short* __restrict__ wkh, const unsigned short* __restrict__ wkl,
        const unsigned short* __restrict__ wvh,
        const float* __restrict__ bq, const float* __restrict__ bk, const float* __restrict__ bv,
        unsigned short* __restrict__ qfrag, unsigned short* __restrict__ kfrag,
        unsigned short* __restrict__ vfrag) {
    __shared__ float xs[64][36];
    __shared__ unsigned short xhf[16 * 512];
    __shared__ unsigned short xlf[16 * 512];
    __shared__ unsigned short ts[2][32][40];

    const int t = threadIdx.x, lane = t & 63, li = lane & 31, hi = lane >> 5, w = t >> 6;
    const int nblk = blockIdx.x, b = blockIdx.y;
    const int n0 = nblk * 32;

    for (int cb = 0; cb < 4; ++cb) {
        {
            int c = t >> 3, n4 = (t & 7) * 4;
            float4 v = *reinterpret_cast<const float4*>(
                &x[(size_t)(b * CIN + cb * 64 + c) * NPIX + n0 + n4]);
            xs[c][n4 + 0] = v.x; xs[c][n4 + 1] = v.y;
            xs[c][n4 + 2] = v.z; xs[c][n4 + 3] = v.w;
        }
        __syncthreads();
        {
            const int kc = w & 3;
            const bool isL = (w >= 4);
            short8 f;
#pragma unroll
            for (int e = 0; e < 8; ++e) {
                float v = xs[kc * 16 + hi * 8 + e][li];
                unsigned short hb = f2bf(v);
                f[e] = isL ? (short)f2bf(v - bf2f(hb)) : (short)hb;
            }
            unsigned short* dst = isL ? xlf : xhf;
            *reinterpret_cast<short8*>(&dst[(cb * 4 + kc) * 512 + lane * 8]) = f;
        }
        __syncthreads();
    }

    if (w < 2) {
        const unsigned short* wh = (w == 0) ? wqh : wkh;
        const unsigned short* wl = (w == 0) ? wql : wkl;
        const float* bias = (w == 0) ? bq : bk;
        f32x16 acc;
#pragma unroll
        for (int r = 0; r < 16; ++r) acc[r] = 0.f;
        for (int kc = 0; kc < 16; ++kc) {
            short8 ah = *reinterpret_cast<const short8*>(&xhf[kc * 512 + lane * 8]);
            short8 al = *reinterpret_cast<const short8*>(&xlf[kc * 512 + lane * 8]);
            short8 whf = *reinterpret_cast<const short8*>(&wh[kc * 512 + lane * 8]);
            short8 wlf = *reinterpret_cast<const short8*>(&wl[kc * 512 + lane * 8]);
            acc = __builtin_amdgcn_mfma_f32_32x32x16_bf16(ah, whf, acc, 0, 0, 0);
            acc = __builtin_amdgcn_mfma_f32_32x32x16_bf16(al, whf, acc, 0, 0, 0);
            acc = __builtin_amdgcn_mfma_f32_32x32x16_bf16(ah, wlf, acc, 0, 0, 0);
        }
        const float bs = bias[li];
#pragma unroll
        for (int r = 0; r < 16; ++r) {
            int row = (r & 3) + 8 * (r >> 2) + 4 * hi;
            ts[w][row][li] = f2bf(acc[r] + bs);
        }
        unsigned short* dstf = (w == 0) ? qfrag : kfrag;
#pragma unroll
        for (int dh = 0; dh < 2; ++dh) {
            short8 f = *reinterpret_cast<const short8*>(&ts[w][li][dh * 16 + hi * 8]);
            *reinterpret_cast<short8*>(
                &dstf[((size_t)(b * 128 + nblk) * 2 + dh) * 512 + lane * 8]) = f;
        }
    } else {
        const int w2 = w - 2;
        const int njob = (w2 < 2) ? 2 : 1;
        for (int jj = 0; jj < njob; ++jj) {
            const int cblk = w2 + jj * 6;
            f32x16 acc;
#pragma unroll
            for (int r = 0; r < 16; ++r) acc[r] = 0.f;
            for (int kc = 0; kc < 16; ++kc) {
                short8 xb = *reinterpret_cast<const short8*>(&xhf[kc * 512 + lane * 8]);
                short8 wf = *reinterpret_cast<const short8*>(&wvh[(cblk * 16 + kc) * 512 + lane * 8]);
                acc = __builtin_amdgcn_mfma_f32_32x32x16_bf16(xb, wf, acc, 0, 0, 0);
            }
            const float bvv = bv[cblk * 32 + li];
#pragma unroll
            for (int g = 0; g < 2; ++g) {
                short8 sv;
#pragma unroll
                for (int e = 0; e < 8; ++e) sv[e] = (short)f2bf(acc[g * 8 + e] + bvv);
                *reinterpret_cast<short8*>(
                    &vfrag[((size_t)(b * 8 + cblk) * 256 + nblk * 2 + g) * 512 + lane * 8]) = sv;
            }
        }
    }
}

// ---------------------------------------------------------------------------
// Fused attention, j-split, 768 threads (12 waves = 4 E + 8 PV), 2 blocks/CU.
// Role branches fully separated so E-path temps and PV accumulators share
// physical registers (live ranges disjoint) -> no spills under the 80-reg cap.
// Barrier counts matched: 18 per branch.
__global__ __launch_bounds__(768, 6) void attnv_kernel(
        const unsigned short* __restrict__ qfrag, const unsigned short* __restrict__ kfrag,
        const unsigned short* __restrict__ vfrag, unsigned short* __restrict__ opart,
        float* __restrict__ lpart, float* __restrict__ out) {
    __shared__ unsigned short Ps[4 * 8 * 512];   // [it*2+buf][jg 8][lane*8], 32 KB
    __shared__ float sred[2][4][32];

    const int t = threadIdx.x, lane = t & 63, li = lane & 31, hi = lane >> 5, w = t >> 6;
    const int blk = blockIdx.x;
    const int xcd = blk & 7, slot = blk >> 3;
    const int jh = slot & 1, ps = slot >> 1;
    const int b = xcd >> 1;
    const int ipos = (xcd & 1) * 32 + ps;          // 64-i tile in [0,64)

    if (w < 4) {
        // ---------------- E waves: produce exp(QK^T) into Ps ----------------
        const int sl = w & 3;                      // 32-j slice of the 128-j step
        short8 qb[2][2];
#pragma unroll
        for (int it = 0; it < 2; ++it) {
            size_t qoff = ((size_t)(b * 128 + ipos * 2 + it) * 2) * 512 + lane * 8;
            qb[it][0] = *reinterpret_cast<const short8*>(&qfrag[qoff]);
            qb[it][1] = *reinterpret_cast<const short8*>(&qfrag[qoff + 512]);
        }
        float ssum[2] = {0.f, 0.f};

        auto do_E = [&](int s) {
            const int buf = s & 1;
            size_t koff = ((size_t)(b * 128 + jh * 64 + s * 4 + sl) * 2) * 512 + lane * 8;
            short8 k0 = *reinterpret_cast<const short8*>(&kfrag[koff]);
            short8 k1 = *reinterpret_cast<const short8*>(&kfrag[koff + 512]);
#pragma unroll
            for (int it = 0; it < 2; ++it) {
                f32x16 e;
#pragma unroll
                for (int r = 0; r < 16; ++r) e[r] = 0.f;
                e = __builtin_amdgcn_mfma_f32_32x32x16_bf16(k0, qb[it][0], e, 0, 0, 0);
                e = __builtin_amdgcn_mfma_f32_32x32x16_bf16(k1, qb[it][1], e, 0, 0, 0);
#pragma unroll
                for (int g = 0; g < 2; ++g) {
                    short8 pv8;
#pragma unroll
                    for (int e2 = 0; e2 < 8; ++e2) {
                        float pe = __expf(e[g * 8 + e2]);
                        ssum[it] += pe;
                        pv8[e2] = (short)f2bf(pe);
                    }
                    *reinterpret_cast<short8*>(
                        &Ps[((it * 2 + buf) * 8 + sl * 2 + g) * 512 + lane * 8]) = pv8;
                }
            }
        };

        do_E(0);
        __syncthreads();                           // (1)
#pragma unroll 1
        for (int s = 0; s < 16; ++s) {
            if (s + 1 < 16) do_E(s + 1);
            __syncthreads();                       // (2..17)
        }
#pragma unroll
        for (int it = 0; it < 2; ++it) {
            ssum[it] += __shfl_xor(ssum[it], 32);
            if (lane < 32) sred[it][sl][li] = ssum[it];
        }
        __syncthreads();                           // (18)
        if (sl == 0 && lane < 32) {
#pragma unroll
            for (int it = 0; it < 2; ++it) {
                float lt = sred[it][0][li] + sred[it][1][li] + sred[it][2][li] + sred[it][3][li];
                lpart[((size_t)jh * 4 + b) * NPIX + ipos * 64 + it * 32 + li] = lt;
            }
        }
    } else {
        // ---------------- PV waves: acc += V * P over the j range ----------------
        const int cq = w - 4;                      // 32-c chunk
        f32x16 acc0, acc1;
#pragma unroll
        for (int r = 0; r < 16; ++r) { acc0[r] = 0.f; acc1[r] = 0.f; }

        __syncthreads();                           // (1)
#pragma unroll 1
        for (int s = 0; s < 16; ++s) {
            const int buf = s & 1;
            size_t vbase = ((size_t)(b * 8 + cq) * 256 + jh * 128 + s * 8) * 512 + lane * 8;
            short8 vcur = *reinterpret_cast<const short8*>(&vfrag[vbase]);
#pragma unroll
            for (int kc = 0; kc < 8; ++kc) {
                short8 vnext;
                if (kc < 7) vnext = *reinterpret_cast<const short8*>(&vfrag[vbase + (kc + 1) * 512]);
                short8 B0 = *reinterpret_cast<const short8*>(&Ps[(buf * 8 + kc) * 512 + lane * 8]);
                short8 B1 = *reinterpret_cast<const short8*>(&Ps[((2 + buf) * 8 + kc) * 512 + lane * 8]);
                acc0 = __builtin_amdgcn_mfma_f32_32x32x16_bf16(vcur, B0, acc0, 0, 0, 0);
                acc1 = __builtin_amdgcn_mfma_f32_32x32x16_bf16(vcur, B1, acc1, 0, 0, 0);
                vcur = vnext;
            }
            __syncthreads();                       // (2..17)
        }
        __syncthreads();                           // (18)

        // partial O (linear [b][c][i]): jh0 fp32 parked in out, jh1 bf16 in opart
#pragma unroll
        for (int it = 0; it < 2; ++it) {
            const f32x16& A = it ? acc1 : acc0;
#pragma unroll
            for (int r = 0; r < 16; ++r) {
                int c = cq * 32 + (r & 3) + 8 * (r >> 2) + 4 * hi;
                size_t idx = (size_t)(b * CIN + c) * NPIX + ipos * 64 + it * 32 + li;
                if (jh == 0) out[idx] = A[r];
                else         opart[idx] = f2bf(A[r]);
            }
        }
    }
}

// ---------------------------------------------------------------------------
// Merge: out = gamma * (O0 + O1) / (l0 + l1) + x.  Pure streaming, ~59 MB.
// grid 4096, block 256; thread handles 4 consecutive i.
__global__ __launch_bounds__(256) void merge_kernel(
        const unsigned short* __restrict__ opart, const float* __restrict__ lpart,
        const float* __restrict__ xin, const float* __restrict__ gamma,
        float* __restrict__ out) {
    const size_t idx4 = ((size_t)blockIdx.x * 256 + threadIdx.x) * 4;
    const size_t i  = idx4 & (NPIX - 1);
    const size_t b  = idx4 >> 20;                 // idx4 / (CIN*NPIX)
    float4 o0 = *reinterpret_cast<const float4*>(&out[idx4]);
    float4 xv = *reinterpret_cast<const float4*>(&xin[idx4]);
    float4 l0 = *reinterpret_cast<const float4*>(&lpart[b * NPIX + i]);
    float4 l1 = *reinterpret_cast<const float4*>(&lpart[(4 + b) * NPIX + i]);
    const unsigned short* op = &opart[idx4];
    const float g = gamma[0];
    float4 o;
    o.x = g * (o0.x + bf2f(op[0])) / (l0.x + l1.x) + xv.x;
    o.y = g * (o0.y + bf2f(op[1])) / (l0.y + l1.y) + xv.y;
    o.z = g * (o0.z + bf2f(op[2])) / (l0.z + l1.z) + xv.z;
    o.w = g * (o0.w + bf2f(op[3])) / (l0.w + l1.w) + xv.w;
    *reinterpret_cast<float4*>(&out[idx4]) = o;
}

extern "C" void kernel_launch(void* const* d_in, const int* in_sizes, int n_in,
                              void* d_out, int out_size, void* d_ws, size_t ws_size,
                              hipStream_t stream) {
    const float* x     = (const float*)d_in[0];
    const float* wq    = (const float*)d_in[1];
    const float* bq    = (const float*)d_in[2];
    const float* wk    = (const float*)d_in[3];
    const float* bk    = (const float*)d_in[4];
    const float* wv    = (const float*)d_in[5];
    const float* bv    = (const float*)d_in[6];
    const float* gamma = (const float*)d_in[7];
    float* out = (float*)d_out;

    unsigned short* qf    = (unsigned short*)d_ws;       // 1 MB
    unsigned short* kf    = qf + (size_t)524288;         // 1 MB
    unsigned short* vf    = kf + (size_t)524288;         // 8 MB
    unsigned short* wqh   = vf + (size_t)4194304;
    unsigned short* wql   = wqh + 8192;
    unsigned short* wkh   = wql + 8192;
    unsigned short* wkl   = wkh + 8192;
    unsigned short* wvh   = wkl + 8192;                  // 160 KB of weight frags
    unsigned short* opart = wvh + 65536;                 // 8.4 MB (jh1 bf16 partial O)
    float*          lpart = (float*)(opart + 4194304);   // 128 KB
    // total ~18.8 MB of d_ws

    wprep_kernel<<<dim3(16, 12), 64, 0, stream>>>(wq, wk, wv, wqh, wql, wkh, wkl, wvh);
    projall_kernel<<<dim3(128, 4), 512, 0, stream>>>(x, wqh, wql, wkh, wkl, wvh,
                                                     bq, bk, bv, qf, kf, vf);
    attnv_kernel<<<dim3(512), 768, 0, stream>>>(qf, kf, vf, opart, lpart, out);
    merge_kernel<<<dim3(4096), 256, 0, stream>>>(opart, lpart, x, gamma, out);
}

// Round 9
// 143.638 us; speedup vs baseline: 4.8673x; 1.0120x over previous
//
#include <hip/hip_runtime.h>
#include <hip/hip_bf16.h>

#define NPIX 4096
#define CIN  256
#define DK   32

typedef __attribute__((ext_vector_type(8))) short short8;     // 8 bf16 = one MFMA A/B frag reg group
typedef __attribute__((ext_vector_type(16))) float f32x16;    // 32x32 C/D frag

__device__ __forceinline__ unsigned short f2bf(float f) {
    unsigned int u = __float_as_uint(f);
    return (unsigned short)((u + 0x7fffu + ((u >> 16) & 1u)) >> 16);   // RNE
}
__device__ __forceinline__ float bf2f(unsigned short h) {
    return __uint_as_float(((unsigned int)h) << 16);
}
// packed fp32x2 -> bf16x2 via v_cvt_pk_bf16_f32 (RNE), low short = a
__device__ __forceinline__ unsigned int f2bf2(float a, float b) {
    __hip_bfloat162 h = __float22bfloat162_rn(make_float2(a, b));
    unsigned int u;
    __builtin_memcpy(&u, &h, 4);
    return u;
}

// ---------------------------------------------------------------------------
// Weight prep: wq/wk hi+residual B-frags, wv hi B-frags.
// grid (16 kchunks, 12), 64 threads.
__global__ void wprep_kernel(const float* __restrict__ wq, const float* __restrict__ wk,
                             const float* __restrict__ wv,
                             unsigned short* __restrict__ wqh, unsigned short* __restrict__ wql,
                             unsigned short* __restrict__ wkh, unsigned short* __restrict__ wkl,
                             unsigned short* __restrict__ wvh) {
    const int lane = threadIdx.x & 63, li = lane & 31, hi = lane >> 5;
    const int kc = blockIdx.x, y = blockIdx.y;
    if (y < 4) {
        const float* m = (y < 2) ? wq : wk;
        short8 h8, l8;
#pragma unroll
        for (int e = 0; e < 8; ++e) {
            float v = m[li * CIN + kc * 16 + hi * 8 + e];
            unsigned short hb = f2bf(v);
            h8[e] = (short)hb;
            l8[e] = (short)f2bf(v - bf2f(hb));
        }
        unsigned short* dst = (y == 0) ? wqh : (y == 1) ? wql : (y == 2) ? wkh : wkl;
        *reinterpret_cast<short8*>(&dst[kc * 512 + lane * 8]) = (y & 1) ? l8 : h8;
    } else {
        const int cblk = y - 4;
        short8 h8;
#pragma unroll
        for (int e = 0; e < 8; ++e)
            h8[e] = (short)f2bf(wv[(cblk * 32 + li) * CIN + kc * 16 + hi * 8 + e]);
        *reinterpret_cast<short8*>(&wvh[(cblk * 16 + kc) * 512 + lane * 8]) = h8;
    }
}

// ---------------------------------------------------------------------------
// Fused prep + Q/K/V projection (unchanged). grid (128, 4), block 512.
__global__ __launch_bounds__(512) void projall_kernel(
        const float* __restrict__ x,
        const unsigned short* __restrict__ wqh, const unsigned short* __restrict__ wql,
        const unsigned short* __restrict__ wkh, const unsigned short* __restrict__ wkl,
        const unsigned short* __restrict__ wvh,
        const float* __restrict__ bq, const float* __restrict__ bk, const float* __restrict__ bv,
        unsigned short* __restrict__ qfrag, unsigned short* __restrict__ kfrag,
        unsigned short* __restrict__ vfrag) {
    __shared__ float xs[64][36];
    __shared__ unsigned short xhf[16 * 512];
    __shared__ unsigned short xlf[16 * 512];
    __shared__ unsigned short ts[2][32][40];

    const int t = threadIdx.x, lane = t & 63, li = lane & 31, hi = lane >> 5, w = t >> 6;
    const int nblk = blockIdx.x, b = blockIdx.y;
    const int n0 = nblk * 32;

    for (int cb = 0; cb < 4; ++cb) {
        {
            int c = t >> 3, n4 = (t & 7) * 4;
            float4 v = *reinterpret_cast<const float4*>(
                &x[(size_t)(b * CIN + cb * 64 + c) * NPIX + n0 + n4]);
            xs[c][n4 + 0] = v.x; xs[c][n4 + 1] = v.y;
            xs[c][n4 + 2] = v.z; xs[c][n4 + 3] = v.w;
        }
        __syncthreads();
        {
            const int kc = w & 3;
            const bool isL = (w >= 4);
            short8 f;
#pragma unroll
            for (int e = 0; e < 8; ++e) {
                float v = xs[kc * 16 + hi * 8 + e][li];
                unsigned short hb = f2bf(v);
                f[e] = isL ? (short)f2bf(v - bf2f(hb)) : (short)hb;
            }
            unsigned short* dst = isL ? xlf : xhf;
            *reinterpret_cast<short8*>(&dst[(cb * 4 + kc) * 512 + lane * 8]) = f;
        }
        __syncthreads();
    }

    if (w < 2) {
        const unsigned short* wh = (w == 0) ? wqh : wkh;
        const unsigned short* wl = (w == 0) ? wql : wkl;
        const float* bias = (w == 0) ? bq : bk;
        f32x16 acc;
#pragma unroll
        for (int r = 0; r < 16; ++r) acc[r] = 0.f;
        for (int kc = 0; kc < 16; ++kc) {
            short8 ah = *reinterpret_cast<const short8*>(&xhf[kc * 512 + lane * 8]);
            short8 al = *reinterpret_cast<const short8*>(&xlf[kc * 512 + lane * 8]);
            short8 whf = *reinterpret_cast<const short8*>(&wh[kc * 512 + lane * 8]);
            short8 wlf = *reinterpret_cast<const short8*>(&wl[kc * 512 + lane * 8]);
            acc = __builtin_amdgcn_mfma_f32_32x32x16_bf16(ah, whf, acc, 0, 0, 0);
            acc = __builtin_amdgcn_mfma_f32_32x32x16_bf16(al, whf, acc, 0, 0, 0);
            acc = __builtin_amdgcn_mfma_f32_32x32x16_bf16(ah, wlf, acc, 0, 0, 0);
        }
        const float bs = bias[li];
#pragma unroll
        for (int r = 0; r < 16; ++r) {
            int row = (r & 3) + 8 * (r >> 2) + 4 * hi;
            ts[w][row][li] = f2bf(acc[r] + bs);
        }
        unsigned short* dstf = (w == 0) ? qfrag : kfrag;
#pragma unroll
        for (int dh = 0; dh < 2; ++dh) {
            short8 f = *reinterpret_cast<const short8*>(&ts[w][li][dh * 16 + hi * 8]);
            *reinterpret_cast<short8*>(
                &dstf[((size_t)(b * 128 + nblk) * 2 + dh) * 512 + lane * 8]) = f;
        }
    } else {
        const int w2 = w - 2;
        const int njob = (w2 < 2) ? 2 : 1;
        for (int jj = 0; jj < njob; ++jj) {
            const int cblk = w2 + jj * 6;
            f32x16 acc;
#pragma unroll
            for (int r = 0; r < 16; ++r) acc[r] = 0.f;
            for (int kc = 0; kc < 16; ++kc) {
                short8 xb = *reinterpret_cast<const short8*>(&xhf[kc * 512 + lane * 8]);
                short8 wf = *reinterpret_cast<const short8*>(&wvh[(cblk * 16 + kc) * 512 + lane * 8]);
                acc = __builtin_amdgcn_mfma_f32_32x32x16_bf16(xb, wf, acc, 0, 0, 0);
            }
            const float bvv = bv[cblk * 32 + li];
#pragma unroll
            for (int g = 0; g < 2; ++g) {
                short8 sv;
#pragma unroll
                for (int e = 0; e < 8; ++e) sv[e] = (short)f2bf(acc[g * 8 + e] + bvv);
                *reinterpret_cast<short8*>(
                    &vfrag[((size_t)(b * 8 + cblk) * 256 + nblk * 2 + g) * 512 + lane * 8]) = sv;
            }
        }
    }
}

// ---------------------------------------------------------------------------
// Fused attention, j-split. Block = 512 threads (8 waves): 4 E waves (one 32-j
// slice each, both i-tiles) + 4 PV waves (64 c each, both i-tiles; halves the
// P LDS-read amplification vs 32c waves). 2 blocks/CU, matched barriers (18).
__global__ __launch_bounds__(512, 4) void attnv_kernel(
        const unsigned short* __restrict__ qfrag, const unsigned short* __restrict__ kfrag,
        const unsigned short* __restrict__ vfrag, unsigned short* __restrict__ opart,
        float* __restrict__ lpart, float* __restrict__ out) {
    __shared__ unsigned short Ps[4 * 8 * 512];   // [it*2+buf][jg 8][lane*8], 32 KB
    __shared__ float sred[2][4][32];

    const int t = threadIdx.x, lane = t & 63, li = lane & 31, hi = lane >> 5, w = t >> 6;
    const int blk = blockIdx.x;
    const int xcd = blk & 7, slot = blk >> 3;
    const int jh = slot & 1, ps = slot >> 1;
    const int b = xcd >> 1;
    const int ipos = (xcd & 1) * 32 + ps;          // 64-i tile in [0,64)

    if (w < 4) {
        // ---------------- E waves: produce exp(QK^T) into Ps ----------------
        const int sl = w;                          // 32-j slice of the 128-j step
        short8 qb[2][2];
#pragma unroll
        for (int it = 0; it < 2; ++it) {
            size_t qoff = ((size_t)(b * 128 + ipos * 2 + it) * 2) * 512 + lane * 8;
            qb[it][0] = *reinterpret_cast<const short8*>(&qfrag[qoff]);
            qb[it][1] = *reinterpret_cast<const short8*>(&qfrag[qoff + 512]);
        }
        float ssum[2] = {0.f, 0.f};

        auto do_E = [&](int s) {
            const int buf = s & 1;
            size_t koff = ((size_t)(b * 128 + jh * 64 + s * 4 + sl) * 2) * 512 + lane * 8;
            short8 k0 = *reinterpret_cast<const short8*>(&kfrag[koff]);
            short8 k1 = *reinterpret_cast<const short8*>(&kfrag[koff + 512]);
#pragma unroll
            for (int it = 0; it < 2; ++it) {
                f32x16 e;
#pragma unroll
                for (int r = 0; r < 16; ++r) e[r] = 0.f;
                e = __builtin_amdgcn_mfma_f32_32x32x16_bf16(k0, qb[it][0], e, 0, 0, 0);
                e = __builtin_amdgcn_mfma_f32_32x32x16_bf16(k1, qb[it][1], e, 0, 0, 0);
#pragma unroll
                for (int g = 0; g < 2; ++g) {
                    float p0 = __expf(e[g * 8 + 0]), p1 = __expf(e[g * 8 + 1]);
                    float p2 = __expf(e[g * 8 + 2]), p3 = __expf(e[g * 8 + 3]);
                    float p4 = __expf(e[g * 8 + 4]), p5 = __expf(e[g * 8 + 5]);
                    float p6 = __expf(e[g * 8 + 6]), p7 = __expf(e[g * 8 + 7]);
                    ssum[it] += ((p0 + p1) + (p2 + p3)) + ((p4 + p5) + (p6 + p7));
                    uint4 pk;
                    pk.x = f2bf2(p0, p1); pk.y = f2bf2(p2, p3);
                    pk.z = f2bf2(p4, p5); pk.w = f2bf2(p6, p7);
                    *reinterpret_cast<uint4*>(
                        &Ps[((it * 2 + buf) * 8 + sl * 2 + g) * 512 + lane * 8]) = pk;
                }
            }
        };

        do_E(0);
        __syncthreads();                           // (1)
#pragma unroll 1
        for (int s = 0; s < 16; ++s) {
            if (s + 1 < 16) do_E(s + 1);
            __syncthreads();                       // (2..17)
        }
#pragma unroll
        for (int it = 0; it < 2; ++it) {
            ssum[it] += __shfl_xor(ssum[it], 32);
            if (lane < 32) sred[it][sl][li] = ssum[it];
        }
        __syncthreads();                           // (18)
        if (sl == 0 && lane < 32) {
#pragma unroll
            for (int it = 0; it < 2; ++it) {
                float lt = sred[it][0][li] + sred[it][1][li] + sred[it][2][li] + sred[it][3][li];
                lpart[((size_t)jh * 4 + b) * NPIX + ipos * 64 + it * 32 + li] = lt;
            }
        }
    } else {
        // -------- PV waves: 64 c each; each P LDS read feeds 4 MFMA --------
        const int cq2 = w - 4;                     // 64-c chunk
        f32x16 acc00, acc01, acc10, acc11;         // [csub][it]
#pragma unroll
        for (int r = 0; r < 16; ++r) { acc00[r] = 0.f; acc01[r] = 0.f; acc10[r] = 0.f; acc11[r] = 0.f; }

        __syncthreads();                           // (1)
#pragma unroll 1
        for (int s = 0; s < 16; ++s) {
            const int buf = s & 1;
            size_t vb0 = ((size_t)(b * 8 + cq2 * 2)     * 256 + jh * 128 + s * 8) * 512 + lane * 8;
            size_t vb1 = ((size_t)(b * 8 + cq2 * 2 + 1) * 256 + jh * 128 + s * 8) * 512 + lane * 8;
            const unsigned short* p0 = &Ps[(buf * 8) * 512 + lane * 8];
            const unsigned short* p1 = &Ps[((2 + buf) * 8) * 512 + lane * 8];
#pragma unroll
            for (int kc = 0; kc < 8; ++kc) {
                short8 B0 = *reinterpret_cast<const short8*>(p0 + kc * 512);
                short8 B1 = *reinterpret_cast<const short8*>(p1 + kc * 512);
                short8 v0 = *reinterpret_cast<const short8*>(&vfrag[vb0 + kc * 512]);
                short8 v1 = *reinterpret_cast<const short8*>(&vfrag[vb1 + kc * 512]);
                acc00 = __builtin_amdgcn_mfma_f32_32x32x16_bf16(v0, B0, acc00, 0, 0, 0);
                acc01 = __builtin_amdgcn_mfma_f32_32x32x16_bf16(v0, B1, acc01, 0, 0, 0);
                acc10 = __builtin_amdgcn_mfma_f32_32x32x16_bf16(v1, B0, acc10, 0, 0, 0);
                acc11 = __builtin_amdgcn_mfma_f32_32x32x16_bf16(v1, B1, acc11, 0, 0, 0);
            }
            __syncthreads();                       // (2..17)
        }
        __syncthreads();                           // (18)

        // partial O (linear [b][c][i]): jh0 fp32 parked in out, jh1 bf16 in opart
#pragma unroll
        for (int cs = 0; cs < 2; ++cs) {
#pragma unroll
            for (int it = 0; it < 2; ++it) {
                const f32x16& A = (cs == 0) ? (it == 0 ? acc00 : acc01)
                                            : (it == 0 ? acc10 : acc11);
#pragma unroll
                for (int r = 0; r < 16; ++r) {
                    int c = cq2 * 64 + cs * 32 + (r & 3) + 8 * (r >> 2) + 4 * hi;
                    size_t idx = (size_t)(b * CIN + c) * NPIX + ipos * 64 + it * 32 + li;
                    if (jh == 0) out[idx] = A[r];
                    else         opart[idx] = f2bf(A[r]);
                }
            }
        }
    }
}

// ---------------------------------------------------------------------------
// Merge: out = gamma * (O0 + O1) / (l0 + l1) + x.  Pure streaming, ~59 MB.
// grid 4096, block 256; thread handles 4 consecutive i.
__global__ __launch_bounds__(256) void merge_kernel(
        const unsigned short* __restrict__ opart, const float* __restrict__ lpart,
        const float* __restrict__ xin, const float* __restrict__ gamma,
        float* __restrict__ out) {
    const size_t idx4 = ((size_t)blockIdx.x * 256 + threadIdx.x) * 4;
    const size_t i  = idx4 & (NPIX - 1);
    const size_t b  = idx4 >> 20;                 // idx4 / (CIN*NPIX)
    float4 o0 = *reinterpret_cast<const float4*>(&out[idx4]);
    float4 xv = *reinterpret_cast<const float4*>(&xin[idx4]);
    float4 l0 = *reinterpret_cast<const float4*>(&lpart[b * NPIX + i]);
    float4 l1 = *reinterpret_cast<const float4*>(&lpart[(4 + b) * NPIX + i]);
    const unsigned short* op = &opart[idx4];
    const float g = gamma[0];
    float4 o;
    o.x = g * (o0.x + bf2f(op[0])) / (l0.x + l1.x) + xv.x;
    o.y = g * (o0.y + bf2f(op[1])) / (l0.y + l1.y) + xv.y;
    o.z = g * (o0.z + bf2f(op[2])) / (l0.z + l1.z) + xv.z;
    o.w = g * (o0.w + bf2f(op[3])) / (l0.w + l1.w) + xv.w;
    *reinterpret_cast<float4*>(&out[idx4]) = o;
}

extern "C" void kernel_launch(void* const* d_in, const int* in_sizes, int n_in,
                              void* d_out, int out_size, void* d_ws, size_t ws_size,
                              hipStream_t stream) {
    const float* x     = (const float*)d_in[0];
    const float* wq    = (const float*)d_in[1];
    const float* bq    = (const float*)d_in[2];
    const float* wk    = (const float*)d_in[3];
    const float* bk    = (const float*)d_in[4];
    const float* wv    = (const float*)d_in[5];
    const float* bv    = (const float*)d_in[6];
    const float* gamma = (const float*)d_in[7];
    float* out = (float*)d_out;

    unsigned short* qf    = (unsigned short*)d_ws;       // 1 MB
    unsigned short* kf    = qf + (size_t)524288;         // 1 MB
    unsigned short* vf    = kf + (size_t)524288;         // 8 MB
    unsigned short* wqh   = vf + (size_t)4194304;
    unsigned short* wql   = wqh + 8192;
    unsigned short* wkh   = wql + 8192;
    unsigned short* wkl   = wkh + 8192;
    unsigned short* wvh   = wkl + 8192;                  // 160 KB of weight frags
    unsigned short* opart = wvh + 65536;                 // 8.4 MB (jh1 bf16 partial O)
    float*          lpart = (float*)(opart + 4194304);   // 128 KB
    // total ~18.8 MB of d_ws

    wprep_kernel<<<dim3(16, 12), 64, 0, stream>>>(wq, wk, wv, wqh, wql, wkh, wkl, wvh);
    projall_kernel<<<dim3(128, 4), 512, 0, stream>>>(x, wqh, wql, wkh, wkl, wvh,
                                                     bq, bk, bv, qf, kf, vf);
    attnv_kernel<<<dim3(512), 512, 0, stream>>>(qf, kf, vf, opart, lpart, out);
    merge_kernel<<<dim3(4096), 256, 0, stream>>>(opart, lpart, x, gamma, out);
}

// Round 10
// 140.391 us; speedup vs baseline: 4.9798x; 1.0231x over previous
//
#include <hip/hip_runtime.h>
#include <hip/hip_bf16.h>

#define NPIX 4096
#define CIN  256
#define DK   32

typedef __attribute__((ext_vector_type(8))) short short8;     // 8 bf16 = one MFMA A/B frag reg group
typedef __attribute__((ext_vector_type(16))) float f32x16;    // 32x32 C/D frag

__device__ __forceinline__ unsigned short f2bf(float f) {
    unsigned int u = __float_as_uint(f);
    return (unsigned short)((u + 0x7fffu + ((u >> 16) & 1u)) >> 16);   // RNE
}
__device__ __forceinline__ float bf2f(unsigned short h) {
    return __uint_as_float(((unsigned int)h) << 16);
}
// packed fp32x2 -> bf16x2 via v_cvt_pk_bf16_f32 (RNE), low short = a
__device__ __forceinline__ unsigned int f2bf2(float a, float b) {
    __hip_bfloat162 h = __float22bfloat162_rn(make_float2(a, b));
    unsigned int u;
    __builtin_memcpy(&u, &h, 4);
    return u;
}

// ---------------------------------------------------------------------------
// Weight prep: wq/wk hi+residual B-frags, wv hi B-frags.
// grid (16 kchunks, 12), 64 threads.
__global__ void wprep_kernel(const float* __restrict__ wq, const float* __restrict__ wk,
                             const float* __restrict__ wv,
                             unsigned short* __restrict__ wqh, unsigned short* __restrict__ wql,
                             unsigned short* __restrict__ wkh, unsigned short* __restrict__ wkl,
                             unsigned short* __restrict__ wvh) {
    const int lane = threadIdx.x & 63, li = lane & 31, hi = lane >> 5;
    const int kc = blockIdx.x, y = blockIdx.y;
    if (y < 4) {
        const float* m = (y < 2) ? wq : wk;
        short8 h8, l8;
#pragma unroll
        for (int e = 0; e < 8; ++e) {
            float v = m[li * CIN + kc * 16 + hi * 8 + e];
            unsigned short hb = f2bf(v);
            h8[e] = (short)hb;
            l8[e] = (short)f2bf(v - bf2f(hb));
        }
        unsigned short* dst = (y == 0) ? wqh : (y == 1) ? wql : (y == 2) ? wkh : wkl;
        *reinterpret_cast<short8*>(&dst[kc * 512 + lane * 8]) = (y & 1) ? l8 : h8;
    } else {
        const int cblk = y - 4;
        short8 h8;
#pragma unroll
        for (int e = 0; e < 8; ++e)
            h8[e] = (short)f2bf(wv[(cblk * 32 + li) * CIN + kc * 16 + hi * 8 + e]);
        *reinterpret_cast<short8*>(&wvh[(cblk * 16 + kc) * 512 + lane * 8]) = h8;
    }
}

// ---------------------------------------------------------------------------
// Fused prep + Q/K/V projection (unchanged). grid (128, 4), block 512.
__global__ __launch_bounds__(512) void projall_kernel(
        const float* __restrict__ x,
        const unsigned short* __restrict__ wqh, const unsigned short* __restrict__ wql,
        const unsigned short* __restrict__ wkh, const unsigned short* __restrict__ wkl,
        const unsigned short* __restrict__ wvh,
        const float* __restrict__ bq, const float* __restrict__ bk, const float* __restrict__ bv,
        unsigned short* __restrict__ qfrag, unsigned short* __restrict__ kfrag,
        unsigned short* __restrict__ vfrag) {
    __shared__ float xs[64][36];
    __shared__ unsigned short xhf[16 * 512];
    __shared__ unsigned short xlf[16 * 512];
    __shared__ unsigned short ts[2][32][40];

    const int t = threadIdx.x, lane = t & 63, li = lane & 31, hi = lane >> 5, w = t >> 6;
    const int nblk = blockIdx.x, b = blockIdx.y;
    const int n0 = nblk * 32;

    for (int cb = 0; cb < 4; ++cb) {
        {
            int c = t >> 3, n4 = (t & 7) * 4;
            float4 v = *reinterpret_cast<const float4*>(
                &x[(size_t)(b * CIN + cb * 64 + c) * NPIX + n0 + n4]);
            xs[c][n4 + 0] = v.x; xs[c][n4 + 1] = v.y;
            xs[c][n4 + 2] = v.z; xs[c][n4 + 3] = v.w;
        }
        __syncthreads();
        {
            const int kc = w & 3;
            const bool isL = (w >= 4);
            short8 f;
#pragma unroll
            for (int e = 0; e < 8; ++e) {
                float v = xs[kc * 16 + hi * 8 + e][li];
                unsigned short hb = f2bf(v);
                f[e] = isL ? (short)f2bf(v - bf2f(hb)) : (short)hb;
            }
            unsigned short* dst = isL ? xlf : xhf;
            *reinterpret_cast<short8*>(&dst[(cb * 4 + kc) * 512 + lane * 8]) = f;
        }
        __syncthreads();
    }

    if (w < 2) {
        const unsigned short* wh = (w == 0) ? wqh : wkh;
        const unsigned short* wl = (w == 0) ? wql : wkl;
        const float* bias = (w == 0) ? bq : bk;
        f32x16 acc;
#pragma unroll
        for (int r = 0; r < 16; ++r) acc[r] = 0.f;
        for (int kc = 0; kc < 16; ++kc) {
            short8 ah = *reinterpret_cast<const short8*>(&xhf[kc * 512 + lane * 8]);
            short8 al = *reinterpret_cast<const short8*>(&xlf[kc * 512 + lane * 8]);
            short8 whf = *reinterpret_cast<const short8*>(&wh[kc * 512 + lane * 8]);
            short8 wlf = *reinterpret_cast<const short8*>(&wl[kc * 512 + lane * 8]);
            acc = __builtin_amdgcn_mfma_f32_32x32x16_bf16(ah, whf, acc, 0, 0, 0);
            acc = __builtin_amdgcn_mfma_f32_32x32x16_bf16(al, whf, acc, 0, 0, 0);
            acc = __builtin_amdgcn_mfma_f32_32x32x16_bf16(ah, wlf, acc, 0, 0, 0);
        }
        const float bs = bias[li];
#pragma unroll
        for (int r = 0; r < 16; ++r) {
            int row = (r & 3) + 8 * (r >> 2) + 4 * hi;
            ts[w][row][li] = f2bf(acc[r] + bs);
        }
        unsigned short* dstf = (w == 0) ? qfrag : kfrag;
#pragma unroll
        for (int dh = 0; dh < 2; ++dh) {
            short8 f = *reinterpret_cast<const short8*>(&ts[w][li][dh * 16 + hi * 8]);
            *reinterpret_cast<short8*>(
                &dstf[((size_t)(b * 128 + nblk) * 2 + dh) * 512 + lane * 8]) = f;
        }
    } else {
        const int w2 = w - 2;
        const int njob = (w2 < 2) ? 2 : 1;
        for (int jj = 0; jj < njob; ++jj) {
            const int cblk = w2 + jj * 6;
            f32x16 acc;
#pragma unroll
            for (int r = 0; r < 16; ++r) acc[r] = 0.f;
            for (int kc = 0; kc < 16; ++kc) {
                short8 xb = *reinterpret_cast<const short8*>(&xhf[kc * 512 + lane * 8]);
                short8 wf = *reinterpret_cast<const short8*>(&wvh[(cblk * 16 + kc) * 512 + lane * 8]);
                acc = __builtin_amdgcn_mfma_f32_32x32x16_bf16(xb, wf, acc, 0, 0, 0);
            }
            const float bvv = bv[cblk * 32 + li];
#pragma unroll
            for (int g = 0; g < 2; ++g) {
                short8 sv;
#pragma unroll
                for (int e = 0; e < 8; ++e) sv[e] = (short)f2bf(acc[g * 8 + e] + bvv);
                *reinterpret_cast<short8*>(
                    &vfrag[((size_t)(b * 8 + cblk) * 256 + nblk * 2 + g) * 512 + lane * 8]) = sv;
            }
        }
    }
}

// ---------------------------------------------------------------------------
// Fused attention, j-split, SYMMETRIC waves: block = 512 threads (8 waves),
// every wave does one E-unit (it=w>>2, sl=w&3: 32j x 32i exp tile) AND one
// PV-unit (cq=w: 32 c, both i-tiles). Equal per-step work -> no barrier convoy.
// K-frags and all 8 V-frags register-prefetched one full step ahead (cross-
// barrier latency coverage). 2 blocks/CU.
__global__ __launch_bounds__(512, 4) void attnv_kernel(
        const unsigned short* __restrict__ qfrag, const unsigned short* __restrict__ kfrag,
        const unsigned short* __restrict__ vfrag, unsigned short* __restrict__ opart,
        float* __restrict__ lpart, float* __restrict__ out) {
    __shared__ unsigned short Ps[4 * 8 * 512];   // [it*2+buf][jg 8][lane*8], 32 KB
    __shared__ float sred[2][4][32];

    const int t = threadIdx.x, lane = t & 63, li = lane & 31, hi = lane >> 5, w = t >> 6;
    const int blk = blockIdx.x;
    const int xcd = blk & 7, slot = blk >> 3;
    const int jh = slot & 1, ps = slot >> 1;
    const int b = xcd >> 1;
    const int ipos = (xcd & 1) * 32 + ps;          // 64-i tile in [0,64)
    const int it = w >> 2, sl = w & 3;             // E unit
    const int cq = w;                              // PV unit (32 c)

    // persistent Q frag (E unit's i-tile)
    short8 qb0, qb1;
    {
        size_t qoff = ((size_t)(b * 128 + ipos * 2 + it) * 2) * 512 + lane * 8;
        qb0 = *reinterpret_cast<const short8*>(&qfrag[qoff]);
        qb1 = *reinterpret_cast<const short8*>(&qfrag[qoff + 512]);
    }
    float ssum = 0.f;

    f32x16 acc0, acc1;
#pragma unroll
    for (int r = 0; r < 16; ++r) { acc0[r] = 0.f; acc1[r] = 0.f; }

    short8 kp0, kp1;                               // K prefetch (for step s of do_E)
    short8 vp[8];                                  // V prefetch (for step s of PV)

    auto kload = [&](int s) {
        size_t koff = ((size_t)(b * 128 + jh * 64 + s * 4 + sl) * 2) * 512 + lane * 8;
        kp0 = *reinterpret_cast<const short8*>(&kfrag[koff]);
        kp1 = *reinterpret_cast<const short8*>(&kfrag[koff + 512]);
    };
    auto vload = [&](int s) {
        size_t vb = ((size_t)(b * 8 + cq) * 256 + jh * 128 + s * 8) * 512 + lane * 8;
#pragma unroll
        for (int kc = 0; kc < 8; ++kc)
            vp[kc] = *reinterpret_cast<const short8*>(&vfrag[vb + kc * 512]);
    };
    auto do_E = [&](int s) {                       // consumes kp0/kp1 (preloaded for s)
        f32x16 e;
#pragma unroll
        for (int r = 0; r < 16; ++r) e[r] = 0.f;
        e = __builtin_amdgcn_mfma_f32_32x32x16_bf16(kp0, qb0, e, 0, 0, 0);
        e = __builtin_amdgcn_mfma_f32_32x32x16_bf16(kp1, qb1, e, 0, 0, 0);
        const int buf = s & 1;
#pragma unroll
        for (int g = 0; g < 2; ++g) {
            float p0 = __expf(e[g * 8 + 0]), p1 = __expf(e[g * 8 + 1]);
            float p2 = __expf(e[g * 8 + 2]), p3 = __expf(e[g * 8 + 3]);
            float p4 = __expf(e[g * 8 + 4]), p5 = __expf(e[g * 8 + 5]);
            float p6 = __expf(e[g * 8 + 6]), p7 = __expf(e[g * 8 + 7]);
            ssum += ((p0 + p1) + (p2 + p3)) + ((p4 + p5) + (p6 + p7));
            uint4 pk;
            pk.x = f2bf2(p0, p1); pk.y = f2bf2(p2, p3);
            pk.z = f2bf2(p4, p5); pk.w = f2bf2(p6, p7);
            *reinterpret_cast<uint4*>(
                &Ps[((it * 2 + buf) * 8 + sl * 2 + g) * 512 + lane * 8]) = pk;
        }
    };

    kload(0);
    vload(0);
    do_E(0);
    kload(1);
    __syncthreads();                               // (1)

#pragma unroll 1
    for (int s = 0; s < 16; ++s) {
        if (s + 1 < 16) {
            do_E(s + 1);                           // writes buf (s+1)&1; kp holds step s+1
            if (s + 2 < 16) kload(s + 2);
        }
        // PV(s): consume vp (prefetched last iteration) + Ps buf s&1
        const int buf = s & 1;
#pragma unroll
        for (int kc = 0; kc < 8; ++kc) {
            short8 B0 = *reinterpret_cast<const short8*>(&Ps[(buf * 8 + kc) * 512 + lane * 8]);
            short8 B1 = *reinterpret_cast<const short8*>(&Ps[((2 + buf) * 8 + kc) * 512 + lane * 8]);
            acc0 = __builtin_amdgcn_mfma_f32_32x32x16_bf16(vp[kc], B0, acc0, 0, 0, 0);
            acc1 = __builtin_amdgcn_mfma_f32_32x32x16_bf16(vp[kc], B1, acc1, 0, 0, 0);
        }
        if (s + 1 < 16) vload(s + 1);              // issued now, consumed after next barrier
        __syncthreads();                           // (2..17)
    }

    // row sums: wave w holds (it, sl) partial over its 32-j slice
    ssum += __shfl_xor(ssum, 32);
    if (lane < 32) sred[it][sl][li] = ssum;
    __syncthreads();                               // (18)
    if (sl == 0 && lane < 32) {
        float lt = sred[it][0][li] + sred[it][1][li] + sred[it][2][li] + sred[it][3][li];
        lpart[((size_t)jh * 4 + b) * NPIX + ipos * 64 + it * 32 + li] = lt;
    }

    // partial O (linear [b][c][i]): jh0 fp32 parked in out, jh1 bf16 in opart
#pragma unroll
    for (int itt = 0; itt < 2; ++itt) {
        const f32x16& A = itt ? acc1 : acc0;
#pragma unroll
        for (int r = 0; r < 16; ++r) {
            int c = cq * 32 + (r & 3) + 8 * (r >> 2) + 4 * hi;
            size_t idx = (size_t)(b * CIN + c) * NPIX + ipos * 64 + itt * 32 + li;
            if (jh == 0) out[idx] = A[r];
            else         opart[idx] = f2bf(A[r]);
        }
    }
}

// ---------------------------------------------------------------------------
// Merge: out = gamma * (O0 + O1) / (l0 + l1) + x.  Pure streaming, ~59 MB.
// grid 4096, block 256; thread handles 4 consecutive i.
__global__ __launch_bounds__(256) void merge_kernel(
        const unsigned short* __restrict__ opart, const float* __restrict__ lpart,
        const float* __restrict__ xin, const float* __restrict__ gamma,
        float* __restrict__ out) {
    const size_t idx4 = ((size_t)blockIdx.x * 256 + threadIdx.x) * 4;
    const size_t i  = idx4 & (NPIX - 1);
    const size_t b  = idx4 >> 20;                 // idx4 / (CIN*NPIX)
    float4 o0 = *reinterpret_cast<const float4*>(&out[idx4]);
    float4 xv = *reinterpret_cast<const float4*>(&xin[idx4]);
    float4 l0 = *reinterpret_cast<const float4*>(&lpart[b * NPIX + i]);
    float4 l1 = *reinterpret_cast<const float4*>(&lpart[(4 + b) * NPIX + i]);
    const unsigned short* op = &opart[idx4];
    const float g = gamma[0];
    float4 o;
    o.x = g * (o0.x + bf2f(op[0])) / (l0.x + l1.x) + xv.x;
    o.y = g * (o0.y + bf2f(op[1])) / (l0.y + l1.y) + xv.y;
    o.z = g * (o0.z + bf2f(op[2])) / (l0.z + l1.z) + xv.z;
    o.w = g * (o0.w + bf2f(op[3])) / (l0.w + l1.w) + xv.w;
    *reinterpret_cast<float4*>(&out[idx4]) = o;
}

extern "C" void kernel_launch(void* const* d_in, const int* in_sizes, int n_in,
                              void* d_out, int out_size, void* d_ws, size_t ws_size,
                              hipStream_t stream) {
    const float* x     = (const float*)d_in[0];
    const float* wq    = (const float*)d_in[1];
    const float* bq    = (const float*)d_in[2];
    const float* wk    = (const float*)d_in[3];
    const float* bk    = (const float*)d_in[4];
    const float* wv    = (const float*)d_in[5];
    const float* bv    = (const float*)d_in[6];
    const float* gamma = (const float*)d_in[7];
    float* out = (float*)d_out;

    unsigned short* qf    = (unsigned short*)d_ws;       // 1 MB
    unsigned short* kf    = qf + (size_t)524288;         // 1 MB
    unsigned short* vf    = kf + (size_t)524288;         // 8 MB
    unsigned short* wqh   = vf + (size_t)4194304;
    unsigned short* wql   = wqh + 8192;
    unsigned short* wkh   = wql + 8192;
    unsigned short* wkl   = wkh + 8192;
    unsigned short* wvh   = wkl + 8192;                  // 160 KB of weight frags
    unsigned short* opart = wvh + 65536;                 // 8.4 MB (jh1 bf16 partial O)
    float*          lpart = (float*)(opart + 4194304);   // 128 KB
    // total ~18.8 MB of d_ws

    wprep_kernel<<<dim3(16, 12), 64, 0, stream>>>(wq, wk, wv, wqh, wql, wkh, wkl, wvh);
    projall_kernel<<<dim3(128, 4), 512, 0, stream>>>(x, wqh, wql, wkh, wkl, wvh,
                                                     bq, bk, bv, qf, kf, vf);
    attnv_kernel<<<dim3(512), 512, 0, stream>>>(qf, kf, vf, opart, lpart, out);
    merge_kernel<<<dim3(4096), 256, 0, stream>>>(opart, lpart, x, gamma, out);
}